// Round 10
// baseline (194.191 us; speedup 1.0000x reference)
//
#include <hip/hip_runtime.h>
#include <hip/hip_bf16.h>
#include <math.h>

// Problem constants: B=2, S=2048, E=1024, NH=4, DH=256
#define Bb  2
#define Ss  2048
#define Ee  1024
#define NHh 4
#define DHh 256
#define BH  (Bb*NHh)      // 8
#define TI  64            // i-rows per tile (main + fallback)
#define TIB 128           // i-rows per block (big2 fallback path)
#define TJ  32            // j-cols per iteration
#define NT2 (Ss/TI)       // 32 i-tiles per bh
#define NJT (Ss/TJ)       // 64 j-tiles per bh

typedef short        s8v   __attribute__((ext_vector_type(8)));   // 8 bf16 (A/B frag)
typedef float        f4v   __attribute__((ext_vector_type(4)));   // 16x16 acc
typedef float        f16v  __attribute__((ext_vector_type(16)));  // 32x32 acc
typedef unsigned int u4v   __attribute__((ext_vector_type(4)));   // 16B LDS write
typedef unsigned int u2v   __attribute__((ext_vector_type(2)));   // 8B LDS write

// fp32 pair -> packed bf16x2 via HW v_cvt_pk_bf16_f32 (a = low 16)
__device__ inline unsigned pkbf2(float a, float b) {
    __hip_bfloat162 h2 = __float22bfloat162_rn(float2{a, b});
    unsigned u;
    __builtin_memcpy(&u, &h2, 4);
    return u;
}

// async 16B global->LDS DMA; lds arg must be wave-uniform (HW adds lane*16)
__device__ inline void async16(const void* g, void* l) {
    __builtin_amdgcn_global_load_lds(
        (const __attribute__((address_space(1))) void*)g,
        (__attribute__((address_space(3))) void*)l, 16, 0, 0);
}

// ---------------------------------------------------------------------------
// Kernel 1 (fused): blocks 0..255 = gates, TWO weight phases per block:
// stage heads{0,1} weights (48 KB wl, same as r3 - no 96KB LDS trap),
// process 16 rows; restage heads{2,3}, reprocess the SAME rows (row reads
// hit L2, 192 KB/block) -> gates' HBM row traffic halves (96->48 MB) at
// equal per-CU work (256 double blocks == 512 r3 blocks). Blocks 256..767 =
// prep (K/V -> swizzled bf16 images), co-resident with gates (independent).
// ---------------------------------------------------------------------------
__global__ __launch_bounds__(256) void gates_prep_kernel(
    const float* __restrict__ q, const float* __restrict__ k, const float* __restrict__ v,
    const float* __restrict__ igw, const float* __restrict__ igb,
    const float* __restrict__ fgw, const float* __restrict__ fgb,
    float* __restrict__ ig_out, float* __restrict__ fg_out,
    unsigned short* __restrict__ Kimg, unsigned short* __restrict__ Vimg)
{
    int bidx = blockIdx.x;
    int tid = threadIdx.x;

    if (bidx >= 256) {               // ---------------- prep path ----------------
        int pidx = bidx - 256;       // bh*NJT + jt
        int bh = pidx >> 6, jt = pidx & 63;
        int b = bh >> 2, h = bh & 3;
        int J0 = jt * TJ;
        const size_t hoff = (size_t)h * DHh;
        unsigned short* Kt = Kimg + (size_t)pidx * 1024 * 8;
        unsigned short* Vt = Vimg + (size_t)pidx * 1024 * 8;

        // K: chunk(kR,cc) at kR*32 + (cc ^ (kR&7)), holds K[J0+kR][cc*8..+7]
        {
            int kR = tid >> 3, kc0 = tid & 7;
            const float* src = k + ((size_t)(b * Ss + J0 + kR)) * Ee + hoff;
#pragma unroll
            for (int p = 0; p < 4; p++) {
                int cc = kc0 + 8 * p;
                float4 x0 = ((const float4*)(src + cc * 8))[0];
                float4 x1 = ((const float4*)(src + cc * 8))[1];
                u4v wv;
                wv.x = pkbf2(x0.x, x0.y); wv.y = pkbf2(x0.z, x0.w);
                wv.z = pkbf2(x1.x, x1.y); wv.w = pkbf2(x1.z, x1.w);
                *(u4v*)&Kt[(kR * 32 + (cc ^ (kR & 7))) * 8] = wv;
            }
        }
        // V^T: chunk(d,jc) at d*4 + (jc ^ ((d>>1)&3)), holds V[J0+jc*8+e][d]
        {
            int vdp = tid & 127, vjb = tid >> 7;
            int d0 = vdp * 2;
#pragma unroll
            for (int p = 0; p < 2; p++) {
                int jc = vjb + 2 * p;
                const float* vbase = v + ((size_t)(b * Ss + J0 + jc * 8)) * Ee + hoff + d0;
                float2 e0 = *(const float2*)(vbase);
                float2 e1 = *(const float2*)(vbase + Ee);
                float2 e2 = *(const float2*)(vbase + 2 * Ee);
                float2 e3 = *(const float2*)(vbase + 3 * Ee);
                float2 e4 = *(const float2*)(vbase + 4 * Ee);
                float2 e5 = *(const float2*)(vbase + 5 * Ee);
                float2 e6 = *(const float2*)(vbase + 6 * Ee);
                float2 e7 = *(const float2*)(vbase + 7 * Ee);
                int swz = jc ^ (vdp & 3);
                u4v w0, w1;
                w0.x = pkbf2(e0.x, e1.x); w0.y = pkbf2(e2.x, e3.x);
                w0.z = pkbf2(e4.x, e5.x); w0.w = pkbf2(e6.x, e7.x);
                w1.x = pkbf2(e0.y, e1.y); w1.y = pkbf2(e2.y, e3.y);
                w1.z = pkbf2(e4.y, e5.y); w1.w = pkbf2(e6.y, e7.y);
                *(u4v*)&Vt[(d0 * 4 + swz) * 8] = w0;
                *(u4v*)&Vt[((d0 + 1) * 4 + swz) * 8] = w1;
            }
        }
        return;
    }

    // ---------------- gates path: 16 rows, two weight phases ----------------
    int sc = bidx;                     // 0..255, rows [sc*16, sc*16+16)
    __shared__ float wl[4][3072];      // 48 KB
    __shared__ float pw[4][8];

    int c4 = tid * 4;
    int w = tid >> 6, lane = tid & 63;

#pragma unroll 1
    for (int ph = 0; ph < 2; ph++) {
#pragma unroll
        for (int c = 0; c < 4; c++) {
            int h = ph * 2 + (c >> 1);
            const float* src = ((c & 1) ? fgw : igw) + (size_t)h * 3 * Ee;
            for (int idx = tid * 4; idx < 3 * Ee; idx += 1024)
                *(float4*)&wl[c][idx] = *(const float4*)(src + idx);
        }
        __syncthreads();

        for (int sp = 0; sp < 8; sp++) {
            int bs0 = sc * 16 + sp * 2;
            float4 qa = *(const float4*)(q + (size_t)bs0 * Ee + c4);
            float4 ka = *(const float4*)(k + (size_t)bs0 * Ee + c4);
            float4 va = *(const float4*)(v + (size_t)bs0 * Ee + c4);
            float4 qb = *(const float4*)(q + (size_t)(bs0 + 1) * Ee + c4);
            float4 kb = *(const float4*)(k + (size_t)(bs0 + 1) * Ee + c4);
            float4 vb = *(const float4*)(v + (size_t)(bs0 + 1) * Ee + c4);
            float red[8];
#pragma unroll
            for (int c = 0; c < 4; c++) {
                const float* wc = wl[c];
                float4 wq = *(const float4*)&wc[c4];
                float4 wk = *(const float4*)&wc[Ee + c4];
                float4 wv = *(const float4*)&wc[2 * Ee + c4];
                float x0 = qa.x*wq.x + qa.y*wq.y + qa.z*wq.z + qa.w*wq.w
                         + ka.x*wk.x + ka.y*wk.y + ka.z*wk.z + ka.w*wk.w
                         + va.x*wv.x + va.y*wv.y + va.z*wv.z + va.w*wv.w;
                float x1 = qb.x*wq.x + qb.y*wq.y + qb.z*wq.z + qb.w*wq.w
                         + kb.x*wk.x + kb.y*wk.y + kb.z*wk.z + kb.w*wk.w
                         + vb.x*wv.x + vb.y*wv.y + vb.z*wv.z + vb.w*wv.w;
                for (int off = 32; off > 0; off >>= 1) {
                    x0 += __shfl_down(x0, off, 64);
                    x1 += __shfl_down(x1, off, 64);
                }
                red[c] = x0; red[4 + c] = x1;
            }
            __syncthreads();
            if (lane == 0) {
#pragma unroll
                for (int c = 0; c < 8; c++) pw[w][c] = red[c];
            }
            __syncthreads();
            if (tid < 8) {
                float t = pw[0][tid] + pw[1][tid] + pw[2][tid] + pw[3][tid];
                int rr = tid >> 2, cc = tid & 3;
                int h = ph * 2 + (cc >> 1);
                int bs = bs0 + rr;
                int b = bs >> 11, s = bs & 2047;
                size_t o = ((size_t)(b * NHh + h)) * Ss + s;
                if (cc & 1) fg_out[o] = t + fgb[h];
                else        ig_out[o] = t + igb[h];
            }
        }
        __syncthreads();   // all reads of wl done before phase-2 restage
    }
}

// ---------------------------------------------------------------------------
// Kernel 2: per-(b,h) scan, wave-shuffle version (8 blocks, 2 barriers).
// ---------------------------------------------------------------------------
#define CHUNK 8
__global__ __launch_bounds__(256) void scan_kernel(
    const float* __restrict__ ig, const float* __restrict__ fg,
    float* __restrict__ a_out, float* __restrict__ M_out, float* __restrict__ nf_out)
{
    int bh = blockIdx.x;
    int tid = threadIdx.x;
    const float* igp = ig + (size_t)bh * Ss;
    const float* fgp = fg + (size_t)bh * Ss;
    int s0 = tid * CHUNK;
    int lane = tid & 63, wv = tid >> 6;

    float ls[CHUNK], cs[CHUNK];
    float tot = 0.f;
#pragma unroll
    for (int c = 0; c < CHUNK; c++) {
        float x = fgp[s0 + c];
        float l = fminf(x, 0.f) - log1pf(expf(-fabsf(x)));
        ls[c] = l; tot += l; cs[c] = tot;
    }
    // inclusive wave scan of tot
    float xs = tot;
#pragma unroll
    for (int off = 1; off < 64; off <<= 1) {
        float y = __shfl_up(xs, off, 64);
        if (lane >= off) xs += y;
    }
    __shared__ float wsum[4];
    if (lane == 63) wsum[wv] = xs;
    __syncthreads();
    float wpre = 0.f;
    for (int i = 0; i < wv; i++) wpre += wsum[i];
    float excl = wpre + xs - tot;      // exclusive prefix over threads

    float av[CHUNK], pmax[CHUNK];
    float tmax = -INFINITY;
#pragma unroll
    for (int c = 0; c < CHUNK; c++) {
        float csf  = excl + cs[c];
        float csm1 = csf - ls[c];
        float a = igp[s0 + c] - csm1;
        av[c] = a;
        tmax = fmaxf(tmax, a);
        pmax[c] = tmax;
        cs[c] = csf;
    }
    // inclusive wave max-scan of tmax
    float xm = tmax;
#pragma unroll
    for (int off = 1; off < 64; off <<= 1) {
        float y = __shfl_up(xm, off, 64);
        if (lane >= off) xm = fmaxf(xm, y);
    }
    __shared__ float wmax[4];
    if (lane == 63) wmax[wv] = xm;
    __syncthreads();
    float mpre = -INFINITY;
    for (int i = 0; i < wv; i++) mpre = fmaxf(mpre, wmax[i]);
    float me = __shfl_up(xm, 1, 64);
    if (lane == 0) me = -INFINITY;
    float emax = fmaxf(mpre, me);

#pragma unroll
    for (int c = 0; c < CHUNK; c++) {
        float M = fmaxf(emax, pmax[c]);
        size_t o = (size_t)bh * Ss + s0 + c;
        a_out[o]  = av[c];
        M_out[o]  = M;
        nf_out[o] = expf(-cs[c] - M);
    }
}

// ---------------------------------------------------------------------------
// Kernel 3 (main path, r7-proven ~58us): 12-wave equal-work residency.
// 1056 iters/bh = 96 chunks x 11 exactly; 768 blocks, 3/CU, zero imbalance.
// ---------------------------------------------------------------------------
__global__ __launch_bounds__(256, 3) void mlstm_ch(
    const float* __restrict__ qp,
    const unsigned short* __restrict__ Kimg, const unsigned short* __restrict__ Vimg,
    const float* __restrict__ a_ws, const float* __restrict__ M_ws,
    float* __restrict__ outF, float* __restrict__ Hpart, float* __restrict__ rsbuf)
{
    int bidx = blockIdx.x;           // 0..767
    int bh = bidx & 7;
    int c  = bidx >> 3;              // chunk 0..95
    int b = bh >> 2, h = bh & 3;
    int tid = threadIdx.x;

    const size_t hoff = (size_t)h * DHh;
    const size_t HP = (size_t)Bb * Ss * Ee;

    __shared__ unsigned short KF[1024 * 8];      // 16 KB (single buffer)
    __shared__ unsigned short VF[1024 * 8];      // 16 KB (single buffer)
    __shared__ unsigned short PF[256 * 8];       // 4 KB (wave-private quarters)
    __shared__ float a_s[TJ];
    __shared__ float rs_s[TI];

    const int iq   = tid >> 6;       // wave id (0..3)
    const int lane = tid & 63;
    const int lm = lane & 15, q4 = lane >> 4;
    const float inv_sqrt_dh = 0.0625f;

    const unsigned short* Kb = Kimg + (size_t)(bh * NJT) * 1024 * 8;
    const unsigned short* Vb = Vimg + (size_t)(bh * NJT) * 1024 * 8;
    const float* a_base = a_ws + (size_t)bh * Ss;

    int g    = c * 11;               // global iter in [0,1056)
    int gend = g + 11;
    // tile containing g: T(T+1) <= g < (T+1)(T+2)
    int T = (int)((sqrtf((float)(4 * g + 1)) - 1.f) * 0.5f);
    while (T * (T + 1) > g) T--;
    while ((T + 1) * (T + 2) <= g) T++;

    while (g < gend) {
        const int tstart = T * (T + 1);
        const int tend   = tstart + 2 * T + 2;
        const int jt_beg = g - tstart;
        const int pend   = (gend < tend) ? gend : tend;
        const int jt_end = pend - tstart;
        const int ord    = c - tstart / 11;     // chunk rank within this tile
        const int I0     = T * TI;
        float* Hdst = (ord == 0) ? outF : (Hpart + (size_t)(ord - 1) * HP);

        // ---- Q fragments in registers (B-operand of S^T = K·Q^T) ----
        s8v qf[8];
        {
            const float* qrow = qp + ((size_t)(b * Ss + I0 + iq * 16 + lm)) * Ee + hoff;
#pragma unroll
            for (int ks = 0; ks < 8; ks++) {
                const float4* p = (const float4*)(qrow + ks * 32 + q4 * 8);
                float4 x0 = p[0], x1 = p[1];
                union { s8v v; unsigned u[4]; } rr;
                rr.u[0] = pkbf2(x0.x, x0.y);
                rr.u[1] = pkbf2(x0.z, x0.w);
                rr.u[2] = pkbf2(x1.x, x1.y);
                rr.u[3] = pkbf2(x1.z, x1.w);
                qf[ks] = rr.v;
            }
        }
        const int  i_row = I0 + iq * 16 + lm;
        const float Mi = M_ws[(size_t)bh * Ss + i_row];

        f4v acc[16];                 // H[i=iq*16+q4*4+rr][d=db*16+lm]
#pragma unroll
        for (int t = 0; t < 16; t++) { acc[t][0]=0.f; acc[t][1]=0.f; acc[t][2]=0.f; acc[t][3]=0.f; }
        float rs_acc = 0.f;

        // piece prologue: K(jt_beg) + a(jt_beg)
        {
            const unsigned short* Kt = Kb + (size_t)jt_beg * 1024 * 8;
#pragma unroll
            for (int p = 0; p < 4; p++) {
                int cbase = (iq * 4 + p) * 64;
                async16(Kt + (size_t)(cbase + lane) * 8, &KF[cbase * 8]);
            }
            if (lane < 2)
                async16(a_base + (size_t)jt_beg * TJ + iq * 8 + lane * 4, &a_s[iq * 8]);
        }
        __syncthreads();   // K+a landed; prev piece's VF reads / rs_s use done

        for (int jt = jt_beg; jt < jt_end; jt++) {
            // issue V(jt) -> VF; lands under the QK phase
            {
                const unsigned short* Vt = Vb + (size_t)jt * 1024 * 8;
#pragma unroll
                for (int p = 0; p < 4; p++) {
                    int cbase = (iq * 4 + p) * 64;
                    async16(Vt + (size_t)(cbase + lane) * 8, &VF[cbase * 8]);
                }
            }
            const int J0 = jt * TJ;

            // ---- QK: S^T [32j x 16i] per wave via mfma 16x16x32 ----
            f4v c0 = {0.f, 0.f, 0.f, 0.f}, c1 = c0;
            __builtin_amdgcn_s_setprio(1);
#pragma unroll
            for (int ks = 0; ks < 8; ks++) {
                int swzk = ((ks * 4 + q4) ^ (lm & 7)) * 8;
                s8v af0 = *(const s8v*)&KF[(lm * 32) * 8 + swzk];
                s8v af1 = *(const s8v*)&KF[((16 + lm) * 32) * 8 + swzk];
                c0 = __builtin_amdgcn_mfma_f32_16x16x32_bf16(af0, qf[ks], c0, 0, 0, 0);
                c1 = __builtin_amdgcn_mfma_f32_16x16x32_bf16(af1, qf[ks], c1, 0, 0, 0);
            }
            __builtin_amdgcn_s_setprio(0);
            // decay + mask + rowsum + pack P into wave-private PF quarter
            {
                float rsum = 0.f;
#pragma unroll
                for (int t = 0; t < 2; t++) {
                    const f4v cc = t ? c1 : c0;
                    const int jb = t * 16 + q4 * 4;
                    float p[4];
#pragma unroll
                    for (int rr = 0; rr < 4; rr++) {
                        int jg = J0 + jb + rr;
                        float pv = 0.f;
                        if (jg <= i_row) pv = cc[rr] * inv_sqrt_dh * __expf(a_s[jb + rr] - Mi);
                        p[rr] = pv; rsum += pv;
                    }
                    u2v pwv;
                    pwv.x = pkbf2(p[0], p[1]);
                    pwv.y = pkbf2(p[2], p[3]);
                    int kb = t * 2 + (q4 >> 1);
                    *(u2v*)&PF[(iq * 64 + lm * 4 + (kb ^ (lm & 3))) * 8 + (q4 & 1) * 4] = pwv;
                }
                rsum += __shfl_xor(rsum, 16);
                rsum += __shfl_xor(rsum, 32);
                rs_acc += rsum;
            }
            // wave-private PF read-back in A-frag order (lgkmcnt-ordered)
            s8v pa = *(const s8v*)&PF[(iq * 64 + lm * 4 + (q4 ^ (lm & 3))) * 8];

            __syncthreads();   // V(jt) landed; all waves done reading KF(jt)

            // issue K(jt+1)+a(jt+1) -> KF; lands under the PV phase
            if (jt + 1 < jt_end) {
                const unsigned short* Kt = Kb + (size_t)(jt + 1) * 1024 * 8;
#pragma unroll
                for (int p = 0; p < 4; p++) {
                    int cbase = (iq * 4 + p) * 64;
                    async16(Kt + (size_t)(cbase + lane) * 8, &KF[cbase * 8]);
                }
                if (lane < 2)
                    async16(a_base + (size_t)(jt + 1) * TJ + iq * 8 + lane * 4, &a_s[iq * 8]);
            }

            // ---- PV: H[16i x 256d] += P[16x32] · V[32x256] ----
            __builtin_amdgcn_s_setprio(1);
#pragma unroll
            for (int db = 0; db < 16; db++) {
                int d = db * 16 + lm;
                s8v vb = *(const s8v*)&VF[(d * 4 + (q4 ^ ((d >> 1) & 3))) * 8];
                acc[db] = __builtin_amdgcn_mfma_f32_16x16x32_bf16(pa, vb, acc[db], 0, 0, 0);
            }
            __builtin_amdgcn_s_setprio(0);

            __syncthreads();   // K(jt+1)+a landed; all waves done reading VF(jt)
        }

        // ---- piece epilogue: rowsums + raw fp32 partial H ----
        if (q4 == 0) rs_s[iq * 16 + lm] = rs_acc;
        __syncthreads();
        if (tid < TI)
            rsbuf[(size_t)ord * BH * Ss + (size_t)bh * Ss + I0 + tid] = rs_s[tid];

#pragma unroll
        for (int rr = 0; rr < 4; rr++) {
            float* row = Hdst + ((size_t)(b * Ss + I0 + iq * 16 + q4 * 4 + rr)) * Ee + hoff + lm;
#pragma unroll
            for (int db = 0; db < 16; db++)
                row[db * 16] = acc[db][rr];
        }

        g = pend;
        if (g >= tend) T++;
    }
}

// ---------------------------------------------------------------------------
// Kernel 3-alt (r3-proven path for 3-slab workspaces): dual-row-set dbuf.
// ---------------------------------------------------------------------------
__global__ __launch_bounds__(256, 2) void mlstm_big2(
    const float* __restrict__ qp,
    const unsigned short* __restrict__ Kimg, const unsigned short* __restrict__ Vimg,
    const float* __restrict__ a_ws, const float* __restrict__ M_ws,
    float* __restrict__ outF, float* __restrict__ Hpart, float* __restrict__ rsbuf)
{
    int bidx = blockIdx.x;
    int qd = bidx >> 7, u = bidx & 127;
    int bh = u & 7;
    int r  = u >> 3;                 // 0..15
    int T  = (qd < 2) ? (15 - r) : r;
    int sg = qd;
    int b = bh >> 2, h = bh & 3;
    int I0 = T * TIB;
    int tid = threadIdx.x;

    const int tot = 4 * T + 4;
    const int jt_beg = (sg * tot) / 4;
    const int jt_end = ((sg + 1) * tot) / 4;
    const size_t hoff = (size_t)h * DHh;
    float* Hdst = (sg == 0) ? outF : (Hpart + (size_t)(sg - 1) * Bb * Ss * Ee);

    __shared__ unsigned short KF[2][1024 * 8];
    __shared__ unsigned short VF[2][1024 * 8];
    __shared__ unsigned short PF[512 * 8];
    __shared__ float a_s[2][TJ];
    __shared__ float rs_s[TIB];

    const int iq   = tid >> 6;
    const int lane = tid & 63;
    const int lm = lane & 15, q4 = lane >> 4;

    s8v qf0[8], qf1[8];
    {
        const float* qrow0 = qp + ((size_t)(b * Ss + I0 + iq * 16 + lm)) * Ee + hoff;
        const float* qrow1 = qrow0 + (size_t)64 * Ee;
#pragma unroll
        for (int ks = 0; ks < 8; ks++) {
            const float4* p0 = (const float4*)(qrow0 + ks * 32 + q4 * 8);
            float4 x0 = p0[0], x1 = p0[1];
            union { s8v v; unsigned u[4]; } rr;
            rr.u[0] = pkbf2(x0.x, x0.y);
            rr.u[1] = pkbf2(x0.z, x0.w);
            rr.u[2] = pkbf2(x1.x, x1.y);
            rr.u[3] = pkbf2(x1.z, x1.w);
            qf0[ks] = rr.v;
            const float4* p1 = (const float4*)(qrow1 + ks * 32 + q4 * 8);
            float4 y0 = p1[0], y1 = p1[1];
            union { s8v v; unsigned u[4]; } ss;
            ss.u[0] = pkbf2(y0.x, y0.y);
            ss.u[1] = pkbf2(y0.z, y0.w);
            ss.u[2] = pkbf2(y1.x, y1.y);
            ss.u[3] = pkbf2(y1.z, y1.w);
            qf1[ks] = ss.v;
        }
    }
    const int  i_row0 = I0 + iq * 16 + lm;
    const int  i_row1 = i_row0 + 64;
    const float Mi0 = M_ws[(size_t)bh * Ss + i_row0];
    const float Mi1 = M_ws[(size_t)bh * Ss + i_row1];

    f4v acc0[16], acc1[16];
#pragma unroll
    for (int t = 0; t < 16; t++) {
        acc0[t][0]=0.f; acc0[t][1]=0.f; acc0[t][2]=0.f; acc0[t][3]=0.f;
        acc1[t][0]=0.f; acc1[t][1]=0.f; acc1[t][2]=0.f; acc1[t][3]=0.f;
    }
    float rs_a0 = 0.f, rs_a1 = 0.f;
    const float inv_sqrt_dh = 0.0625f;

    const unsigned short* Kb = Kimg + (size_t)(bh * NJT) * 1024 * 8;
    const unsigned short* Vb = Vimg + (size_t)(bh * NJT) * 1024 * 8;

    {
        const unsigned short* Kt = Kb + (size_t)jt_beg * 1024 * 8;
        const unsigned short* Vt = Vb + (size_t)jt_beg * 1024 * 8;
#pragma unroll
        for (int p = 0; p < 4; p++) {
            int cbase = (iq * 4 + p) * 64;
            async16(Kt + (size_t)(cbase + lane) * 8, &KF[0][cbase * 8]);
            async16(Vt + (size_t)(cbase + lane) * 8, &VF[0][cbase * 8]);
        }
        if (tid < TJ) a_s[0][tid] = a_ws[(size_t)bh * Ss + jt_beg * TJ + tid];
    }

    int cur = 0;
    for (int jt = jt_beg; jt < jt_end; jt++, cur ^= 1) {
        __syncthreads();

        if (jt + 1 < jt_end) {
            const unsigned short* Kt = Kb + (size_t)(jt + 1) * 1024 * 8;
            const unsigned short* Vt = Vb + (size_t)(jt + 1) * 1024 * 8;
#pragma unroll
            for (int p = 0; p < 4; p++) {
                int cbase = (iq * 4 + p) * 64;
                async16(Kt + (size_t)(cbase + lane) * 8, &KF[cur ^ 1][cbase * 8]);
                async16(Vt + (size_t)(cbase + lane) * 8, &VF[cur ^ 1][cbase * 8]);
            }
            if (tid < TJ) a_s[cur ^ 1][tid] = a_ws[(size_t)bh * Ss + (jt + 1) * TJ + tid];
        }
        const int J0 = jt * TJ;

        f4v c00 = {0.f,0.f,0.f,0.f}, c01 = c00, c10 = c00, c11 = c00;
#pragma unroll
        for (int ks = 0; ks < 8; ks++) {
            int swzk = ((ks * 4 + q4) ^ (lm & 7)) * 8;
            s8v af0 = *(const s8v*)&KF[cur][(lm * 32) * 8 + swzk];
            s8v af1 = *(const s8v*)&KF[cur][((16 + lm) * 32) * 8 + swzk];
            c00 = __builtin_amdgcn_mfma_f32_16x16x32_bf16(af0, qf0[ks], c00, 0, 0, 0);
            c01 = __builtin_amdgcn_mfma_f32_16x16x32_bf16(af1, qf0[ks], c01, 0, 0, 0);
            c10 = __builtin_amdgcn_mfma_f32_16x16x32_bf16(af0, qf1[ks], c10, 0, 0, 0);
            c11 = __builtin_amdgcn_mfma_f32_16x16x32_bf16(af1, qf1[ks], c11, 0, 0, 0);
        }
        {
            float rsum0 = 0.f, rsum1 = 0.f;
#pragma unroll
            for (int t = 0; t < 2; t++) {
                const f4v ca = t ? c01 : c00;
                const f4v cb = t ? c11 : c10;
                const int jb = t * 16 + q4 * 4;
                float p0[4], p1[4];
#pragma unroll
                for (int rr = 0; rr < 4; rr++) {
                    int jg = J0 + jb + rr;
                    float ev = __expf(a_s[cur][jb + rr] - Mi0) * inv_sqrt_dh;
                    float ev1 = __expf(a_s[cur][jb + rr] - Mi1) * inv_sqrt_dh;
                    float pv0 = 0.f, pv1 = 0.f;
                    if (jg <= i_row0) pv0 = ca[rr] * ev;
                    if (jg <= i_row1) pv1 = cb[rr] * ev1;
                    p0[rr] = pv0; rsum0 += pv0;
                    p1[rr] = pv1; rsum1 += pv1;
                }
                int kb = t * 2 + (q4 >> 1);
                int cidx = (iq * 64 + lm * 4 + (kb ^ (lm & 3))) * 8 + (q4 & 1) * 4;
                u2v pw0, pw1;
                pw0.x = pkbf2(p0[0], p0[1]); pw0.y = pkbf2(p0[2], p0[3]);
                pw1.x = pkbf2(p1[0], p1[1]); pw1.y = pkbf2(p1[2], p1[3]);
                *(u2v*)&PF[cidx]            = pw0;
                *(u2v*)&PF[256 * 8 + cidx]  = pw1;
            }
            rsum0 += __shfl_xor(rsum0, 16);
            rsum0 += __shfl_xor(rsum0, 32);
            rs_a0 += rsum0;
            rsum1 += __shfl_xor(rsum1, 16);
            rsum1 += __shfl_xor(rsum1, 32);
            rs_a1 += rsum1;
        }
        int pidx = (iq * 64 + lm * 4 + (q4 ^ (lm & 3))) * 8;
        s8v pa0 = *(const s8v*)&PF[pidx];
        s8v pa1 = *(const s8v*)&PF[256 * 8 + pidx];

#pragma unroll
        for (int db = 0; db < 16; db++) {
            int d = db * 16 + lm;
            s8v vb = *(const s8v*)&VF[cur][(d * 4 + (q4 ^ ((d >> 1) & 3))) * 8];
            acc0[db] = __builtin_amdgcn_mfma_f32_16x16x32_bf16(pa0, vb, acc0[db], 0, 0, 0);
            acc1[db] = __builtin_amdgcn_mfma_f32_16x16x32_bf16(pa1, vb, acc1[db], 0, 0, 0);
        }
    }

    if (q4 == 0) {
        rs_s[iq * 16 + lm] = rs_a0;
        rs_s[64 + iq * 16 + lm] = rs_a1;
    }
    __syncthreads();
    if (tid < TIB)
        rsbuf[(size_t)sg * BH * Ss + (size_t)bh * Ss + I0 + tid] = rs_s[tid];

#pragma unroll
    for (int rr = 0; rr < 4; rr++) {
        float* row0 = Hdst + ((size_t)(b * Ss + I0 + iq * 16 + q4 * 4 + rr)) * Ee + hoff + lm;
        float* row1 = row0 + (size_t)64 * Ee;
#pragma unroll
        for (int db = 0; db < 16; db++) {
            row0[db * 16] = acc0[db][rr];
            row1[db * 16] = acc1[db][rr];
        }
    }
}

// ---------------------------------------------------------------------------
// Kernel 3b (fallback, inline staging, 3-barrier): kept for small workspaces.
// ---------------------------------------------------------------------------
template<int PARTS>
__global__ __launch_bounds__(256, 4) void mlstm_fallback(
    const float* __restrict__ qp, const float* __restrict__ kp, const float* __restrict__ vp,
    const float* __restrict__ a_ws, const float* __restrict__ M_ws,
    float* __restrict__ outF, float* __restrict__ Hpart, float* __restrict__ rsbuf)
{
    int bidx = blockIdx.x;
    int bh, T, sg;
    if (PARTS == 1) {
        bh = bidx & 7; T = (NT2 - 1) - (bidx >> 3); sg = 0;
    } else {
        int qd = bidx >> 8, u = bidx & 255;
        bh = u & 7;
        int r = u >> 3;
        T  = qd ? r : (31 - r);
        sg = r & 1;
    }
    int b = bh >> 2, h = bh & 3;
    int I0 = T * TI;
    int tid = threadIdx.x;

    const int tot = 2 * T + 2;
    const int jt_beg = (sg * tot) / PARTS;
    const int jt_end = ((sg + 1) * tot) / PARTS;
    const size_t hoff = (size_t)h * DHh;
    float* Hdst = (sg == 0) ? outF : (Hpart + (size_t)(sg - 1) * Bb * Ss * Ee);

    if (jt_beg >= jt_end) {
        float4 z = {0.f, 0.f, 0.f, 0.f};
        for (int t = tid; t < TI * 64; t += 256) {
            int r2 = t >> 6, c = t & 63;
            *(float4*)(Hdst + ((size_t)(b * Ss + I0 + r2)) * Ee + hoff + 4 * c) = z;
        }
        if (tid < TI) rsbuf[(size_t)sg * BH * Ss + (size_t)bh * Ss + I0 + tid] = 0.f;
        return;
    }

    __shared__ unsigned short KF[1024 * 8];
    __shared__ unsigned short VF[1024 * 8];
    __shared__ unsigned short PF[256 * 8];
    __shared__ float a_s[TJ];
    __shared__ float rs_s[TI];

    const int iq   = tid >> 6;
    const int lane = tid & 63;
    const int lm = lane & 15, q4 = lane >> 4;
    const int m5 = lane & 31, hl = lane >> 5;

    s8v qf[8];
    {
        const float* qrow = qp + ((size_t)(b * Ss + I0 + iq * 16 + lm)) * Ee + hoff;
#pragma unroll
        for (int ks = 0; ks < 8; ks++) {
            const float4* p = (const float4*)(qrow + ks * 32 + q4 * 8);
            float4 x0 = p[0], x1 = p[1];
            union { s8v v; unsigned u[4]; } rr;
            rr.u[0] = pkbf2(x0.x, x0.y);
            rr.u[1] = pkbf2(x0.z, x0.w);
            rr.u[2] = pkbf2(x1.x, x1.y);
            rr.u[3] = pkbf2(x1.z, x1.w);
            qf[ks] = rr.v;
        }
    }
    const int  i_row = I0 + iq * 16 + lm;
    const float Mi = M_ws[(size_t)bh * Ss + i_row];

    f16v acc[4];
#pragma unroll
    for (int t = 0; t < 4; t++)
#pragma unroll
        for (int i = 0; i < 16; i++) acc[t][i] = 0.f;
    float rs_acc = 0.f;

    const float inv_sqrt_dh = 0.0625f;
    const int kR  = tid >> 3, kc0 = tid & 7;
    const int vdp = tid & 127, vjb = tid >> 7;

    for (int jt = jt_beg; jt < jt_end; jt++) {
        const int J0 = jt * TJ;
        __syncthreads();
        {
            const float* src = kp + ((size_t)(b * Ss + J0 + kR)) * Ee + hoff;
#pragma unroll
            for (int p = 0; p < 4; p++) {
                int cc = kc0 + 8 * p;
                float4 x0 = ((const float4*)(src + cc * 8))[0];
                float4 x1 = ((const float4*)(src + cc * 8))[1];
                u4v wv;
                wv.x = pkbf2(x0.x, x0.y); wv.y = pkbf2(x0.z, x0.w);
                wv.z = pkbf2(x1.x, x1.y); wv.w = pkbf2(x1.z, x1.w);
                *(u4v*)&KF[(kR * 32 + (cc ^ (kR & 7))) * 8] = wv;
            }
            int d0 = vdp * 2;
#pragma unroll
            for (int p = 0; p < 2; p++) {
                int jc = vjb + 2 * p;
                const float* vbase = vp + ((size_t)(b * Ss + J0 + jc * 8)) * Ee + hoff + d0;
                float2 e0 = *(const float2*)(vbase);
                float2 e1 = *(const float2*)(vbase + Ee);
                float2 e2 = *(const float2*)(vbase + 2 * Ee);
                float2 e3 = *(const float2*)(vbase + 3 * Ee);
                float2 e4 = *(const float2*)(vbase + 4 * Ee);
                float2 e5 = *(const float2*)(vbase + 5 * Ee);
                float2 e6 = *(const float2*)(vbase + 6 * Ee);
                float2 e7 = *(const float2*)(vbase + 7 * Ee);
                int swz = jc ^ (vdp & 3);
                u4v w0, w1;
                w0.x = pkbf2(e0.x, e1.x); w0.y = pkbf2(e2.x, e3.x);
                w0.z = pkbf2(e4.x, e5.x); w0.w = pkbf2(e6.x, e7.x);
                w1.x = pkbf2(e0.y, e1.y); w1.y = pkbf2(e2.y, e3.y);
                w1.z = pkbf2(e4.y, e5.y); w1.w = pkbf2(e6.y, e7.y);
                *(u4v*)&VF[(d0 * 4 + swz) * 8] = w0;
                *(u4v*)&VF[((d0 + 1) * 4 + swz) * 8] = w1;
            }
        }
        if (tid < TJ) a_s[tid] = a_ws[(size_t)bh * Ss + J0 + tid];
        __syncthreads();

        f4v c0 = {0.f, 0.f, 0.f, 0.f}, c1 = c0;
#pragma unroll
        for (int ks = 0; ks < 8; ks++) {
            int swzk = ((ks * 4 + q4) ^ (lm & 7)) * 8;
            s8v af0 = *(const s8v*)&KF[(lm * 32) * 8 + swzk];
            s8v af1 = *(const s8v*)&KF[((16 + lm) * 32) * 8 + swzk];
            c0 = __builtin_amdgcn_mfma_f32_16x16x32_bf16(af0, qf[ks], c0, 0, 0, 0);
            c1 = __builtin_amdgcn_mfma_f32_16x16x32_bf16(af1, qf[ks], c1, 0, 0, 0);
        }
        {
            float rsum = 0.f;
#pragma unroll
            for (int t = 0; t < 2; t++) {
                const f4v cc = t ? c1 : c0;
                const int jb = t * 16 + q4 * 4;
                float p[4];
#pragma unroll
                for (int rr = 0; rr < 4; rr++) {
                    int jg = J0 + jb + rr;
                    float pv = 0.f;
                    if (jg <= i_row) pv = cc[rr] * inv_sqrt_dh * __expf(a_s[jb + rr] - Mi);
                    p[rr] = pv; rsum += pv;
                }
                u2v pwv;
                pwv.x = pkbf2(p[0], p[1]);
                pwv.y = pkbf2(p[2], p[3]);
                int i = iq * 16 + lm;
                int kb = t * 2 + (q4 >> 1);
                *(u2v*)&PF[(i * 4 + (kb ^ ((i >> 1) & 3))) * 8 + (q4 & 1) * 4] = pwv;
            }
            rsum += __shfl_xor(rsum, 16);
            rsum += __shfl_xor(rsum, 32);
            rs_acc += rsum;
        }
        __syncthreads();

#pragma unroll
        for (int ks2 = 0; ks2 < 2; ks2++) {
            int swz2 = ((ks2 * 2 + hl) ^ ((m5 >> 1) & 3)) * 8;
            s8v pa0 = *(const s8v*)&PF[(m5 * 4) * 8 + swz2];
            s8v pa1 = *(const s8v*)&PF[((32 + m5) * 4) * 8 + swz2];
            s8v vb0 = *(const s8v*)&VF[((iq * 32 + m5) * 4) * 8 + swz2];
            s8v vb1 = *(const s8v*)&VF[(((iq + 4) * 32 + m5) * 4) * 8 + swz2];
            acc[0] = __builtin_amdgcn_mfma_f32_32x32x16_bf16(pa0, vb0, acc[0], 0, 0, 0);
            acc[1] = __builtin_amdgcn_mfma_f32_32x32x16_bf16(pa0, vb1, acc[1], 0, 0, 0);
            acc[2] = __builtin_amdgcn_mfma_f32_32x32x16_bf16(pa1, vb0, acc[2], 0, 0, 0);
            acc[3] = __builtin_amdgcn_mfma_f32_32x32x16_bf16(pa1, vb1, acc[3], 0, 0, 0);
        }
    }

    if (q4 == 0) rs_s[iq * 16 + lm] = rs_acc;
    __syncthreads();
    if (tid < TI)
        rsbuf[(size_t)sg * BH * Ss + (size_t)bh * Ss + I0 + tid] = rs_s[tid];

#pragma unroll
    for (int im = 0; im < 2; im++)
#pragma unroll
        for (int ns = 0; ns < 2; ns++) {
            const f16v av = acc[im * 2 + ns];
            const int col = (iq + 4 * ns) * 32 + m5;
#pragma unroll
            for (int rr = 0; rr < 16; rr++) {
                int row = I0 + im * 32 + (rr & 3) + 8 * (rr >> 2) + 4 * hl;
                Hdst[((size_t)(b * Ss + row)) * Ee + hoff + col] = av[rr];
            }
        }
}

// ---------------------------------------------------------------------------
// Kernel 4a: combine for the chunked mapping. Per row: TI=64 tile T occupies
// global iters [T(T+1), T(T+1)+2T+2); piece count p = (chunks intersecting)
// = (tend-1)/11 - tstart/11 + 1. Same closed form as the mlstm kernel's ord.
// ---------------------------------------------------------------------------
__global__ __launch_bounds__(256) void combine_ch(
    const float* __restrict__ Hb, const float* __restrict__ rsbuf,
    const float* __restrict__ nf_ws, const float* __restrict__ out_w,
    float* __restrict__ outF)
{
    int rid = blockIdx.x * 4 + (threadIdx.x >> 6);
    int lane = threadIdx.x & 63;
    int bh = rid >> 11, s = rid & 2047;
    int b = bh >> 2, h = bh & 3;
    int T = s >> 6;                      // TI=64 tile index
    int tstart = T * (T + 1);
    int tend   = tstart + 2 * T + 2;
    int p = (tend - 1) / 11 - tstart / 11 + 1;

    size_t base = ((size_t)(b * Ss + s)) * Ee + (size_t)h * DHh + lane * 4;
    const size_t HP = (size_t)Bb * Ss * Ee;
    float4 ha = *(const float4*)(outF + base);
    float rs = rsbuf[(size_t)bh * Ss + s];
    for (int k = 1; k < p; k++) {
        float4 hb = *(const float4*)(Hb + (size_t)(k - 1) * HP + base);
        ha.x += hb.x; ha.y += hb.y; ha.z += hb.z; ha.w += hb.w;
        rs += rsbuf[(size_t)k * BH * Ss + (size_t)bh * Ss + s];
    }
    float nfv = nf_ws[(size_t)bh * Ss + s];
    float invn = 1.f / (fmaxf(fabsf(rs), nfv) + 1e-8f);
    float4 x;
    x.x = ha.x * invn; x.y = ha.y * invn; x.z = ha.z * invn; x.w = ha.w * invn;
    float sx = x.x + x.y + x.z + x.w;
    float sq = x.x*x.x + x.y*x.y + x.z*x.z + x.w*x.w;
#pragma unroll
    for (int off = 1; off < 64; off <<= 1) {
        sx += __shfl_xor(sx, off);
        sq += __shfl_xor(sq, off);
    }
    float mean = sx * (1.f / DHh);
    float var  = sq * (1.f / DHh) - mean * mean;
    float rstd = rsqrtf(var + 1e-5f);
    float4 w4 = *(const float4*)(out_w + (size_t)h * DHh + lane * 4);
    float4 o;
    o.x = (x.x - mean) * rstd * (1.f + w4.x);
    o.y = (x.y - mean) * rstd * (1.f + w4.y);
    o.z = (x.z - mean) * rstd * (1.f + w4.z);
    o.w = (x.w - mean) * rstd * (1.f + w4.w);
    *(float4*)(outF + base) = o;
}

// ---------------------------------------------------------------------------
// Kernel 4b: fixed-PARTS combine (for big2 path and fallbacks).
// ---------------------------------------------------------------------------
template<int PARTS>
__global__ __launch_bounds__(256) void combine_kernel(
    const float* __restrict__ Hb, const float* __restrict__ rsbuf,
    const float* __restrict__ nf_ws, const float* __restrict__ out_w,
    float* __restrict__ outF)
{
    int rid = blockIdx.x * 4 + (threadIdx.x >> 6);
    int lane = threadIdx.x & 63;
    int bh = rid >> 11, s = rid & 2047;
    int b = bh >> 2, h = bh & 3;
    size_t base = ((size_t)(b * Ss + s)) * Ee + (size_t)h * DHh + lane * 4;
    float4 ha = *(const float4*)(outF + base);
    float rs = rsbuf[(size_t)bh * Ss + s];
#pragma unroll
    for (int k = 1; k < PARTS; k++) {
        float4 hb = *(const float4*)(Hb + (size_t)(k - 1) * Bb * Ss * Ee + base);
        ha.x += hb.x; ha.y += hb.y; ha.z += hb.z; ha.w += hb.w;
        rs += rsbuf[(size_t)k * BH * Ss + (size_t)bh * Ss + s];
    }
    float nfv = nf_ws[(size_t)bh * Ss + s];
    float invn = 1.f / (fmaxf(fabsf(rs), nfv) + 1e-8f);
    float4 x;
    x.x = ha.x * invn; x.y = ha.y * invn; x.z = ha.z * invn; x.w = ha.w * invn;
    float sx = x.x + x.y + x.z + x.w;
    float sq = x.x*x.x + x.y*x.y + x.z*x.z + x.w*x.w;
#pragma unroll
    for (int off = 1; off < 64; off <<= 1) {
        sx += __shfl_xor(sx, off);
        sq += __shfl_xor(sq, off);
    }
    float mean = sx * (1.f / DHh);
    float var  = sq * (1.f / DHh) - mean * mean;
    float rstd = rsqrtf(var + 1e-5f);
    float4 w4 = *(const float4*)(out_w + (size_t)h * DHh + lane * 4);
    float4 o;
    o.x = (x.x - mean) * rstd * (1.f + w4.x);
    o.y = (x.y - mean) * rstd * (1.f + w4.y);
    o.z = (x.z - mean) * rstd * (1.f + w4.z);
    o.w = (x.w - mean) * rstd * (1.f + w4.w);
    *(float4*)(outF + base) = o;
}

// ---------------------------------------------------------------------------
extern "C" void kernel_launch(void* const* d_in, const int* in_sizes, int n_in,
                              void* d_out, int out_size, void* d_ws, size_t ws_size,
                              hipStream_t stream) {
    const float* q   = (const float*)d_in[0];
    const float* k   = (const float*)d_in[1];
    const float* v   = (const float*)d_in[2];
    const float* igw = (const float*)d_in[3];
    const float* igb = (const float*)d_in[4];
    const float* fgw = (const float*)d_in[5];
    const float* fgb = (const float*)d_in[6];
    const float* ow  = (const float*)d_in[7];
    float* out = (float*)d_out;

    float* ws = (float*)d_ws;
    float* ig = ws;                     // BH*S floats each
    float* fg = ws + 16384;
    float* aa = ws + 32768;
    float* MM = ws + 49152;
    float* nf = ws + 65536;
    float* rsb = ws + 81920;            // 8 slots x BH*S = 131072 floats
    const size_t base_f = 81920 + 131072;           // 212992 floats
    unsigned short* KimgP = (unsigned short*)(ws + base_f);
    const size_t img_u = (size_t)BH * NJT * 1024 * 8;        // 8.4 MB each (u16)
    unsigned short* VimgP = KimgP + img_u;
    float* HpartImg = (float*)(VimgP + img_u);
    float* HpartRaw = ws + base_f;
    const size_t HP = (size_t)Bb * Ss * Ee;                  // 16.8 MB

    const size_t need_ch = base_f * 4 + 2 * img_u * 2 + 6 * HP * 4;  // ~118 MB
    const size_t need4   = base_f * 4 + 2 * img_u * 2 + 3 * HP * 4;  // ~85 MB
    const size_t need2   = base_f * 4 + 1 * HP * 4;

    if (ws_size >= need_ch) {
        gates_prep_kernel<<<768, 256, 0, stream>>>(q, k, v, igw, igb, fgw, fgb,
                                                   ig, fg, KimgP, VimgP);
        scan_kernel<<<BH, 256, 0, stream>>>(ig, fg, aa, MM, nf);
        mlstm_ch<<<768, 256, 0, stream>>>(q, KimgP, VimgP, aa, MM,
                                          out, HpartImg, rsb);
        combine_ch<<<BH * Ss / 4, 256, 0, stream>>>(HpartImg, rsb, nf, ow, out);
    } else if (ws_size >= need4) {
        gates_prep_kernel<<<768, 256, 0, stream>>>(q, k, v, igw, igb, fgw, fgb,
                                                   ig, fg, KimgP, VimgP);
        scan_kernel<<<BH, 256, 0, stream>>>(ig, fg, aa, MM, nf);
        mlstm_big2<<<512, 256, 0, stream>>>(q, KimgP, VimgP, aa, MM,
                                            out, HpartImg, rsb);
        combine_kernel<4><<<BH * Ss / 4, 256, 0, stream>>>(HpartImg, rsb, nf, ow, out);
    } else if (ws_size >= need2) {
        gates_prep_kernel<<<256, 256, 0, stream>>>(q, k, v, igw, igb, fgw, fgb,
                                                   ig, fg, nullptr, nullptr);
        scan_kernel<<<BH, 256, 0, stream>>>(ig, fg, aa, MM, nf);
        mlstm_fallback<2><<<512, 256, 0, stream>>>(q, k, v, aa, MM, out, HpartRaw, rsb);
        combine_kernel<2><<<BH * Ss / 4, 256, 0, stream>>>(HpartRaw, rsb, nf, ow, out);
    } else {
        gates_prep_kernel<<<256, 256, 0, stream>>>(q, k, v, igw, igb, fgw, fgb,
                                                   ig, fg, nullptr, nullptr);
        scan_kernel<<<BH, 256, 0, stream>>>(ig, fg, aa, MM, nf);
        mlstm_fallback<1><<<256, 256, 0, stream>>>(q, k, v, aa, MM, out, HpartRaw, rsb);
        combine_kernel<1><<<BH * Ss / 4, 256, 0, stream>>>(HpartRaw, rsb, nf, ow, out);
    }
}

// Round 11
// 186.523 us; speedup vs baseline: 1.0411x; 1.0411x over previous
//
#include <hip/hip_runtime.h>
#include <hip/hip_bf16.h>
#include <math.h>

// Problem constants: B=2, S=2048, E=1024, NH=4, DH=256
#define Bb  2
#define Ss  2048
#define Ee  1024
#define NHh 4
#define DHh 256
#define BH  (Bb*NHh)      // 8
#define TI  64            // i-rows per tile (main + fallback)
#define TIB 128           // i-rows per block (big2 fallback path)
#define TJ  32            // j-cols per iteration
#define NT2 (Ss/TI)       // 32 i-tiles per bh
#define NJT (Ss/TJ)       // 64 j-tiles per bh

typedef short        s8v   __attribute__((ext_vector_type(8)));   // 8 bf16 (A/B frag)
typedef float        f4v   __attribute__((ext_vector_type(4)));   // 16x16 acc
typedef float        f16v  __attribute__((ext_vector_type(16)));  // 32x32 acc
typedef unsigned int u4v   __attribute__((ext_vector_type(4)));   // 16B LDS write
typedef unsigned int u2v   __attribute__((ext_vector_type(2)));   // 8B LDS write

// fp32 pair -> packed bf16x2 via HW v_cvt_pk_bf16_f32 (a = low 16)
__device__ inline unsigned pkbf2(float a, float b) {
    __hip_bfloat162 h2 = __float22bfloat162_rn(float2{a, b});
    unsigned u;
    __builtin_memcpy(&u, &h2, 4);
    return u;
}

// async 16B global->LDS DMA; lds arg must be wave-uniform (HW adds lane*16)
__device__ inline void async16(const void* g, void* l) {
    __builtin_amdgcn_global_load_lds(
        (const __attribute__((address_space(1))) void*)g,
        (__attribute__((address_space(3))) void*)l, 16, 0, 0);
}

// ---------------------------------------------------------------------------
// Kernel 1 (fused, r6-champion): blocks 0..511 = gates (weights LDS-staged,
// 16 rows x 2 heads each, 2 rows per barrier-pair); blocks 512..1023 = prep
// (K/V -> swizzled bf16 LDS images). Measured best aux layout (125.7us
// non-mlstm); every rework (r8 128-block, r9 split, r10 two-phase) lost to
// this balance of block count vs per-block work.
// ---------------------------------------------------------------------------
__global__ __launch_bounds__(256) void gates_prep_kernel(
    const float* __restrict__ q, const float* __restrict__ k, const float* __restrict__ v,
    const float* __restrict__ igw, const float* __restrict__ igb,
    const float* __restrict__ fgw, const float* __restrict__ fgb,
    float* __restrict__ ig_out, float* __restrict__ fg_out,
    unsigned short* __restrict__ Kimg, unsigned short* __restrict__ Vimg)
{
    int bidx = blockIdx.x;
    int tid = threadIdx.x;

    if (bidx >= 512) {               // ---------------- prep path ----------------
        int pidx = bidx - 512;       // bh*NJT + jt
        int bh = pidx >> 6, jt = pidx & 63;
        int b = bh >> 2, h = bh & 3;
        int J0 = jt * TJ;
        const size_t hoff = (size_t)h * DHh;
        unsigned short* Kt = Kimg + (size_t)pidx * 1024 * 8;
        unsigned short* Vt = Vimg + (size_t)pidx * 1024 * 8;

        // K: chunk(kR,cc) at kR*32 + (cc ^ (kR&7)), holds K[J0+kR][cc*8..+7]
        {
            int kR = tid >> 3, kc0 = tid & 7;
            const float* src = k + ((size_t)(b * Ss + J0 + kR)) * Ee + hoff;
#pragma unroll
            for (int p = 0; p < 4; p++) {
                int cc = kc0 + 8 * p;
                float4 x0 = ((const float4*)(src + cc * 8))[0];
                float4 x1 = ((const float4*)(src + cc * 8))[1];
                u4v wv;
                wv.x = pkbf2(x0.x, x0.y); wv.y = pkbf2(x0.z, x0.w);
                wv.z = pkbf2(x1.x, x1.y); wv.w = pkbf2(x1.z, x1.w);
                *(u4v*)&Kt[(kR * 32 + (cc ^ (kR & 7))) * 8] = wv;
            }
        }
        // V^T: chunk(d,jc) at d*4 + (jc ^ ((d>>1)&3)), holds V[J0+jc*8+e][d]
        {
            int vdp = tid & 127, vjb = tid >> 7;
            int d0 = vdp * 2;
#pragma unroll
            for (int p = 0; p < 2; p++) {
                int jc = vjb + 2 * p;
                const float* vbase = v + ((size_t)(b * Ss + J0 + jc * 8)) * Ee + hoff + d0;
                float2 e0 = *(const float2*)(vbase);
                float2 e1 = *(const float2*)(vbase + Ee);
                float2 e2 = *(const float2*)(vbase + 2 * Ee);
                float2 e3 = *(const float2*)(vbase + 3 * Ee);
                float2 e4 = *(const float2*)(vbase + 4 * Ee);
                float2 e5 = *(const float2*)(vbase + 5 * Ee);
                float2 e6 = *(const float2*)(vbase + 6 * Ee);
                float2 e7 = *(const float2*)(vbase + 7 * Ee);
                int swz = jc ^ (vdp & 3);
                u4v w0, w1;
                w0.x = pkbf2(e0.x, e1.x); w0.y = pkbf2(e2.x, e3.x);
                w0.z = pkbf2(e4.x, e5.x); w0.w = pkbf2(e6.x, e7.x);
                w1.x = pkbf2(e0.y, e1.y); w1.y = pkbf2(e2.y, e3.y);
                w1.z = pkbf2(e4.y, e5.y); w1.w = pkbf2(e6.y, e7.y);
                *(u4v*)&Vt[(d0 * 4 + swz) * 8] = w0;
                *(u4v*)&Vt[((d0 + 1) * 4 + swz) * 8] = w1;
            }
        }
        return;
    }

    // ---------------- gates path: 2 rows per barrier-pair ----------------
    int sc = bidx >> 1, hp = bidx & 1;
    __shared__ float wl[4][3072];          // 48 KB
    __shared__ float pw[4][8];

#pragma unroll
    for (int c = 0; c < 4; c++) {
        int h = hp * 2 + (c >> 1);
        const float* src = ((c & 1) ? fgw : igw) + (size_t)h * 3 * Ee;
        for (int idx = tid * 4; idx < 3 * Ee; idx += 1024)
            *(float4*)&wl[c][idx] = *(const float4*)(src + idx);
    }
    __syncthreads();

    int c4 = tid * 4;
    int w = tid >> 6, lane = tid & 63;

    for (int sp = 0; sp < 8; sp++) {
        int bs0 = sc * 16 + sp * 2;
        float4 qa = *(const float4*)(q + (size_t)bs0 * Ee + c4);
        float4 ka = *(const float4*)(k + (size_t)bs0 * Ee + c4);
        float4 va = *(const float4*)(v + (size_t)bs0 * Ee + c4);
        float4 qb = *(const float4*)(q + (size_t)(bs0 + 1) * Ee + c4);
        float4 kb = *(const float4*)(k + (size_t)(bs0 + 1) * Ee + c4);
        float4 vb = *(const float4*)(v + (size_t)(bs0 + 1) * Ee + c4);
        float red[8];
#pragma unroll
        for (int c = 0; c < 4; c++) {
            const float* wc = wl[c];
            float4 wq = *(const float4*)&wc[c4];
            float4 wk = *(const float4*)&wc[Ee + c4];
            float4 wv = *(const float4*)&wc[2 * Ee + c4];
            float x0 = qa.x*wq.x + qa.y*wq.y + qa.z*wq.z + qa.w*wq.w
                     + ka.x*wk.x + ka.y*wk.y + ka.z*wk.z + ka.w*wk.w
                     + va.x*wv.x + va.y*wv.y + va.z*wv.z + va.w*wv.w;
            float x1 = qb.x*wq.x + qb.y*wq.y + qb.z*wq.z + qb.w*wq.w
                     + kb.x*wk.x + kb.y*wk.y + kb.z*wk.z + kb.w*wk.w
                     + vb.x*wv.x + vb.y*wv.y + vb.z*wv.z + vb.w*wv.w;
            for (int off = 32; off > 0; off >>= 1) {
                x0 += __shfl_down(x0, off, 64);
                x1 += __shfl_down(x1, off, 64);
            }
            red[c] = x0; red[4 + c] = x1;
        }
        __syncthreads();
        if (lane == 0) {
#pragma unroll
            for (int c = 0; c < 8; c++) pw[w][c] = red[c];
        }
        __syncthreads();
        if (tid < 8) {
            float t = pw[0][tid] + pw[1][tid] + pw[2][tid] + pw[3][tid];
            int rr = tid >> 2, cc = tid & 3;
            int h = hp * 2 + (cc >> 1);
            int bs = bs0 + rr;
            int b = bs >> 11, s = bs & 2047;
            size_t o = ((size_t)(b * NHh + h)) * Ss + s;
            if (cc & 1) fg_out[o] = t + fgb[h];
            else        ig_out[o] = t + igb[h];
        }
    }
}

// ---------------------------------------------------------------------------
// Kernel 2: per-(b,h) scan, wave-shuffle version (8 blocks, 2 barriers;
// verified r9/r10). Strictly cheaper than the old 64-barrier Hillis-Steele.
// ---------------------------------------------------------------------------
#define CHUNK 8
__global__ __launch_bounds__(256) void scan_kernel(
    const float* __restrict__ ig, const float* __restrict__ fg,
    float* __restrict__ a_out, float* __restrict__ M_out, float* __restrict__ nf_out)
{
    int bh = blockIdx.x;
    int tid = threadIdx.x;
    const float* igp = ig + (size_t)bh * Ss;
    const float* fgp = fg + (size_t)bh * Ss;
    int s0 = tid * CHUNK;
    int lane = tid & 63, wv = tid >> 6;

    float ls[CHUNK], cs[CHUNK];
    float tot = 0.f;
#pragma unroll
    for (int c = 0; c < CHUNK; c++) {
        float x = fgp[s0 + c];
        float l = fminf(x, 0.f) - log1pf(expf(-fabsf(x)));
        ls[c] = l; tot += l; cs[c] = tot;
    }
    // inclusive wave scan of tot
    float xs = tot;
#pragma unroll
    for (int off = 1; off < 64; off <<= 1) {
        float y = __shfl_up(xs, off, 64);
        if (lane >= off) xs += y;
    }
    __shared__ float wsum[4];
    if (lane == 63) wsum[wv] = xs;
    __syncthreads();
    float wpre = 0.f;
    for (int i = 0; i < wv; i++) wpre += wsum[i];
    float excl = wpre + xs - tot;      // exclusive prefix over threads

    float av[CHUNK], pmax[CHUNK];
    float tmax = -INFINITY;
#pragma unroll
    for (int c = 0; c < CHUNK; c++) {
        float csf  = excl + cs[c];
        float csm1 = csf - ls[c];
        float a = igp[s0 + c] - csm1;
        av[c] = a;
        tmax = fmaxf(tmax, a);
        pmax[c] = tmax;
        cs[c] = csf;
    }
    // inclusive wave max-scan of tmax
    float xm = tmax;
#pragma unroll
    for (int off = 1; off < 64; off <<= 1) {
        float y = __shfl_up(xm, off, 64);
        if (lane >= off) xm = fmaxf(xm, y);
    }
    __shared__ float wmax[4];
    if (lane == 63) wmax[wv] = xm;
    __syncthreads();
    float mpre = -INFINITY;
    for (int i = 0; i < wv; i++) mpre = fmaxf(mpre, wmax[i]);
    float me = __shfl_up(xm, 1, 64);
    if (lane == 0) me = -INFINITY;
    float emax = fmaxf(mpre, me);

#pragma unroll
    for (int c = 0; c < CHUNK; c++) {
        float M = fmaxf(emax, pmax[c]);
        size_t o = (size_t)bh * Ss + s0 + c;
        a_out[o]  = av[c];
        M_out[o]  = M;
        nf_out[o] = expf(-cs[c] - M);
    }
}

// ---------------------------------------------------------------------------
// Kernel 3 (main path, r7-proven 57-61us): 12-wave equal-work residency.
// 1056 iters/bh = 96 chunks x 11 exactly; 768 blocks, 3/CU, zero imbalance.
// ---------------------------------------------------------------------------
__global__ __launch_bounds__(256, 3) void mlstm_ch(
    const float* __restrict__ qp,
    const unsigned short* __restrict__ Kimg, const unsigned short* __restrict__ Vimg,
    const float* __restrict__ a_ws, const float* __restrict__ M_ws,
    float* __restrict__ outF, float* __restrict__ Hpart, float* __restrict__ rsbuf)
{
    int bidx = blockIdx.x;           // 0..767
    int bh = bidx & 7;
    int c  = bidx >> 3;              // chunk 0..95
    int b = bh >> 2, h = bh & 3;
    int tid = threadIdx.x;

    const size_t hoff = (size_t)h * DHh;
    const size_t HP = (size_t)Bb * Ss * Ee;

    __shared__ unsigned short KF[1024 * 8];      // 16 KB (single buffer)
    __shared__ unsigned short VF[1024 * 8];      // 16 KB (single buffer)
    __shared__ unsigned short PF[256 * 8];       // 4 KB (wave-private quarters)
    __shared__ float a_s[TJ];
    __shared__ float rs_s[TI];

    const int iq   = tid >> 6;       // wave id (0..3)
    const int lane = tid & 63;
    const int lm = lane & 15, q4 = lane >> 4;
    const float inv_sqrt_dh = 0.0625f;

    const unsigned short* Kb = Kimg + (size_t)(bh * NJT) * 1024 * 8;
    const unsigned short* Vb = Vimg + (size_t)(bh * NJT) * 1024 * 8;
    const float* a_base = a_ws + (size_t)bh * Ss;

    int g    = c * 11;               // global iter in [0,1056)
    int gend = g + 11;
    // tile containing g: T(T+1) <= g < (T+1)(T+2)
    int T = (int)((sqrtf((float)(4 * g + 1)) - 1.f) * 0.5f);
    while (T * (T + 1) > g) T--;
    while ((T + 1) * (T + 2) <= g) T++;

    while (g < gend) {
        const int tstart = T * (T + 1);
        const int tend   = tstart + 2 * T + 2;
        const int jt_beg = g - tstart;
        const int pend   = (gend < tend) ? gend : tend;
        const int jt_end = pend - tstart;
        const int ord    = c - tstart / 11;     // chunk rank within this tile
        const int I0     = T * TI;
        float* Hdst = (ord == 0) ? outF : (Hpart + (size_t)(ord - 1) * HP);

        // ---- Q fragments in registers (B-operand of S^T = K·Q^T) ----
        s8v qf[8];
        {
            const float* qrow = qp + ((size_t)(b * Ss + I0 + iq * 16 + lm)) * Ee + hoff;
#pragma unroll
            for (int ks = 0; ks < 8; ks++) {
                const float4* p = (const float4*)(qrow + ks * 32 + q4 * 8);
                float4 x0 = p[0], x1 = p[1];
                union { s8v v; unsigned u[4]; } rr;
                rr.u[0] = pkbf2(x0.x, x0.y);
                rr.u[1] = pkbf2(x0.z, x0.w);
                rr.u[2] = pkbf2(x1.x, x1.y);
                rr.u[3] = pkbf2(x1.z, x1.w);
                qf[ks] = rr.v;
            }
        }
        const int  i_row = I0 + iq * 16 + lm;
        const float Mi = M_ws[(size_t)bh * Ss + i_row];

        f4v acc[16];                 // H[i=iq*16+q4*4+rr][d=db*16+lm]
#pragma unroll
        for (int t = 0; t < 16; t++) { acc[t][0]=0.f; acc[t][1]=0.f; acc[t][2]=0.f; acc[t][3]=0.f; }
        float rs_acc = 0.f;

        // piece prologue: K(jt_beg) + a(jt_beg)
        {
            const unsigned short* Kt = Kb + (size_t)jt_beg * 1024 * 8;
#pragma unroll
            for (int p = 0; p < 4; p++) {
                int cbase = (iq * 4 + p) * 64;
                async16(Kt + (size_t)(cbase + lane) * 8, &KF[cbase * 8]);
            }
            if (lane < 2)
                async16(a_base + (size_t)jt_beg * TJ + iq * 8 + lane * 4, &a_s[iq * 8]);
        }
        __syncthreads();   // K+a landed; prev piece's VF reads / rs_s use done

        for (int jt = jt_beg; jt < jt_end; jt++) {
            // issue V(jt) -> VF; lands under the QK phase
            {
                const unsigned short* Vt = Vb + (size_t)jt * 1024 * 8;
#pragma unroll
                for (int p = 0; p < 4; p++) {
                    int cbase = (iq * 4 + p) * 64;
                    async16(Vt + (size_t)(cbase + lane) * 8, &VF[cbase * 8]);
                }
            }
            const int J0 = jt * TJ;

            // ---- QK: S^T [32j x 16i] per wave via mfma 16x16x32 ----
            f4v c0 = {0.f, 0.f, 0.f, 0.f}, c1 = c0;
            __builtin_amdgcn_s_setprio(1);
#pragma unroll
            for (int ks = 0; ks < 8; ks++) {
                int swzk = ((ks * 4 + q4) ^ (lm & 7)) * 8;
                s8v af0 = *(const s8v*)&KF[(lm * 32) * 8 + swzk];
                s8v af1 = *(const s8v*)&KF[((16 + lm) * 32) * 8 + swzk];
                c0 = __builtin_amdgcn_mfma_f32_16x16x32_bf16(af0, qf[ks], c0, 0, 0, 0);
                c1 = __builtin_amdgcn_mfma_f32_16x16x32_bf16(af1, qf[ks], c1, 0, 0, 0);
            }
            __builtin_amdgcn_s_setprio(0);
            // decay + mask + rowsum + pack P into wave-private PF quarter
            {
                float rsum = 0.f;
#pragma unroll
                for (int t = 0; t < 2; t++) {
                    const f4v cc = t ? c1 : c0;
                    const int jb = t * 16 + q4 * 4;
                    float p[4];
#pragma unroll
                    for (int rr = 0; rr < 4; rr++) {
                        int jg = J0 + jb + rr;
                        float pv = 0.f;
                        if (jg <= i_row) pv = cc[rr] * inv_sqrt_dh * __expf(a_s[jb + rr] - Mi);
                        p[rr] = pv; rsum += pv;
                    }
                    u2v pwv;
                    pwv.x = pkbf2(p[0], p[1]);
                    pwv.y = pkbf2(p[2], p[3]);
                    int kb = t * 2 + (q4 >> 1);
                    *(u2v*)&PF[(iq * 64 + lm * 4 + (kb ^ (lm & 3))) * 8 + (q4 & 1) * 4] = pwv;
                }
                rsum += __shfl_xor(rsum, 16);
                rsum += __shfl_xor(rsum, 32);
                rs_acc += rsum;
            }
            // wave-private PF read-back in A-frag order (lgkmcnt-ordered)
            s8v pa = *(const s8v*)&PF[(iq * 64 + lm * 4 + (q4 ^ (lm & 3))) * 8];

            __syncthreads();   // V(jt) landed; all waves done reading KF(jt)

            // issue K(jt+1)+a(jt+1) -> KF; lands under the PV phase
            if (jt + 1 < jt_end) {
                const unsigned short* Kt = Kb + (size_t)(jt + 1) * 1024 * 8;
#pragma unroll
                for (int p = 0; p < 4; p++) {
                    int cbase = (iq * 4 + p) * 64;
                    async16(Kt + (size_t)(cbase + lane) * 8, &KF[cbase * 8]);
                }
                if (lane < 2)
                    async16(a_base + (size_t)(jt + 1) * TJ + iq * 8 + lane * 4, &a_s[iq * 8]);
            }

            // ---- PV: H[16i x 256d] += P[16x32] · V[32x256] ----
            __builtin_amdgcn_s_setprio(1);
#pragma unroll
            for (int db = 0; db < 16; db++) {
                int d = db * 16 + lm;
                s8v vb = *(const s8v*)&VF[(d * 4 + (q4 ^ ((d >> 1) & 3))) * 8];
                acc[db] = __builtin_amdgcn_mfma_f32_16x16x32_bf16(pa, vb, acc[db], 0, 0, 0);
            }
            __builtin_amdgcn_s_setprio(0);

            __syncthreads();   // K(jt+1)+a landed; all waves done reading VF(jt)
        }

        // ---- piece epilogue: rowsums + raw fp32 partial H ----
        if (q4 == 0) rs_s[iq * 16 + lm] = rs_acc;
        __syncthreads();
        if (tid < TI)
            rsbuf[(size_t)ord * BH * Ss + (size_t)bh * Ss + I0 + tid] = rs_s[tid];

#pragma unroll
        for (int rr = 0; rr < 4; rr++) {
            float* row = Hdst + ((size_t)(b * Ss + I0 + iq * 16 + q4 * 4 + rr)) * Ee + hoff + lm;
#pragma unroll
            for (int db = 0; db < 16; db++)
                row[db * 16] = acc[db][rr];
        }

        g = pend;
        if (g >= tend) T++;
    }
}

// ---------------------------------------------------------------------------
// Kernel 3-alt (r3-proven path for 3-slab workspaces): dual-row-set dbuf.
// ---------------------------------------------------------------------------
__global__ __launch_bounds__(256, 2) void mlstm_big2(
    const float* __restrict__ qp,
    const unsigned short* __restrict__ Kimg, const unsigned short* __restrict__ Vimg,
    const float* __restrict__ a_ws, const float* __restrict__ M_ws,
    float* __restrict__ outF, float* __restrict__ Hpart, float* __restrict__ rsbuf)
{
    int bidx = blockIdx.x;
    int qd = bidx >> 7, u = bidx & 127;
    int bh = u & 7;
    int r  = u >> 3;                 // 0..15
    int T  = (qd < 2) ? (15 - r) : r;
    int sg = qd;
    int b = bh >> 2, h = bh & 3;
    int I0 = T * TIB;
    int tid = threadIdx.x;

    const int tot = 4 * T + 4;
    const int jt_beg = (sg * tot) / 4;
    const int jt_end = ((sg + 1) * tot) / 4;
    const size_t hoff = (size_t)h * DHh;
    float* Hdst = (sg == 0) ? outF : (Hpart + (size_t)(sg - 1) * Bb * Ss * Ee);

    __shared__ unsigned short KF[2][1024 * 8];
    __shared__ unsigned short VF[2][1024 * 8];
    __shared__ unsigned short PF[512 * 8];
    __shared__ float a_s[2][TJ];
    __shared__ float rs_s[TIB];

    const int iq   = tid >> 6;
    const int lane = tid & 63;
    const int lm = lane & 15, q4 = lane >> 4;

    s8v qf0[8], qf1[8];
    {
        const float* qrow0 = qp + ((size_t)(b * Ss + I0 + iq * 16 + lm)) * Ee + hoff;
        const float* qrow1 = qrow0 + (size_t)64 * Ee;
#pragma unroll
        for (int ks = 0; ks < 8; ks++) {
            const float4* p0 = (const float4*)(qrow0 + ks * 32 + q4 * 8);
            float4 x0 = p0[0], x1 = p0[1];
            union { s8v v; unsigned u[4]; } rr;
            rr.u[0] = pkbf2(x0.x, x0.y);
            rr.u[1] = pkbf2(x0.z, x0.w);
            rr.u[2] = pkbf2(x1.x, x1.y);
            rr.u[3] = pkbf2(x1.z, x1.w);
            qf0[ks] = rr.v;
            const float4* p1 = (const float4*)(qrow1 + ks * 32 + q4 * 8);
            float4 y0 = p1[0], y1 = p1[1];
            union { s8v v; unsigned u[4]; } ss;
            ss.u[0] = pkbf2(y0.x, y0.y);
            ss.u[1] = pkbf2(y0.z, y0.w);
            ss.u[2] = pkbf2(y1.x, y1.y);
            ss.u[3] = pkbf2(y1.z, y1.w);
            qf1[ks] = ss.v;
        }
    }
    const int  i_row0 = I0 + iq * 16 + lm;
    const int  i_row1 = i_row0 + 64;
    const float Mi0 = M_ws[(size_t)bh * Ss + i_row0];
    const float Mi1 = M_ws[(size_t)bh * Ss + i_row1];

    f4v acc0[16], acc1[16];
#pragma unroll
    for (int t = 0; t < 16; t++) {
        acc0[t][0]=0.f; acc0[t][1]=0.f; acc0[t][2]=0.f; acc0[t][3]=0.f;
        acc1[t][0]=0.f; acc1[t][1]=0.f; acc1[t][2]=0.f; acc1[t][3]=0.f;
    }
    float rs_a0 = 0.f, rs_a1 = 0.f;
    const float inv_sqrt_dh = 0.0625f;

    const unsigned short* Kb = Kimg + (size_t)(bh * NJT) * 1024 * 8;
    const unsigned short* Vb = Vimg + (size_t)(bh * NJT) * 1024 * 8;

    {
        const unsigned short* Kt = Kb + (size_t)jt_beg * 1024 * 8;
        const unsigned short* Vt = Vb + (size_t)jt_beg * 1024 * 8;
#pragma unroll
        for (int p = 0; p < 4; p++) {
            int cbase = (iq * 4 + p) * 64;
            async16(Kt + (size_t)(cbase + lane) * 8, &KF[0][cbase * 8]);
            async16(Vt + (size_t)(cbase + lane) * 8, &VF[0][cbase * 8]);
        }
        if (tid < TJ) a_s[0][tid] = a_ws[(size_t)bh * Ss + jt_beg * TJ + tid];
    }

    int cur = 0;
    for (int jt = jt_beg; jt < jt_end; jt++, cur ^= 1) {
        __syncthreads();

        if (jt + 1 < jt_end) {
            const unsigned short* Kt = Kb + (size_t)(jt + 1) * 1024 * 8;
            const unsigned short* Vt = Vb + (size_t)(jt + 1) * 1024 * 8;
#pragma unroll
            for (int p = 0; p < 4; p++) {
                int cbase = (iq * 4 + p) * 64;
                async16(Kt + (size_t)(cbase + lane) * 8, &KF[cur ^ 1][cbase * 8]);
                async16(Vt + (size_t)(cbase + lane) * 8, &VF[cur ^ 1][cbase * 8]);
            }
            if (tid < TJ) a_s[cur ^ 1][tid] = a_ws[(size_t)bh * Ss + (jt + 1) * TJ + tid];
        }
        const int J0 = jt * TJ;

        f4v c00 = {0.f,0.f,0.f,0.f}, c01 = c00, c10 = c00, c11 = c00;
#pragma unroll
        for (int ks = 0; ks < 8; ks++) {
            int swzk = ((ks * 4 + q4) ^ (lm & 7)) * 8;
            s8v af0 = *(const s8v*)&KF[cur][(lm * 32) * 8 + swzk];
            s8v af1 = *(const s8v*)&KF[cur][((16 + lm) * 32) * 8 + swzk];
            c00 = __builtin_amdgcn_mfma_f32_16x16x32_bf16(af0, qf0[ks], c00, 0, 0, 0);
            c01 = __builtin_amdgcn_mfma_f32_16x16x32_bf16(af1, qf0[ks], c01, 0, 0, 0);
            c10 = __builtin_amdgcn_mfma_f32_16x16x32_bf16(af0, qf1[ks], c10, 0, 0, 0);
            c11 = __builtin_amdgcn_mfma_f32_16x16x32_bf16(af1, qf1[ks], c11, 0, 0, 0);
        }
        {
            float rsum0 = 0.f, rsum1 = 0.f;
#pragma unroll
            for (int t = 0; t < 2; t++) {
                const f4v ca = t ? c01 : c00;
                const f4v cb = t ? c11 : c10;
                const int jb = t * 16 + q4 * 4;
                float p0[4], p1[4];
#pragma unroll
                for (int rr = 0; rr < 4; rr++) {
                    int jg = J0 + jb + rr;
                    float ev = __expf(a_s[cur][jb + rr] - Mi0) * inv_sqrt_dh;
                    float ev1 = __expf(a_s[cur][jb + rr] - Mi1) * inv_sqrt_dh;
                    float pv0 = 0.f, pv1 = 0.f;
                    if (jg <= i_row0) pv0 = ca[rr] * ev;
                    if (jg <= i_row1) pv1 = cb[rr] * ev1;
                    p0[rr] = pv0; rsum0 += pv0;
                    p1[rr] = pv1; rsum1 += pv1;
                }
                int kb = t * 2 + (q4 >> 1);
                int cidx = (iq * 64 + lm * 4 + (kb ^ (lm & 3))) * 8 + (q4 & 1) * 4;
                u2v pw0, pw1;
                pw0.x = pkbf2(p0[0], p0[1]); pw0.y = pkbf2(p0[2], p0[3]);
                pw1.x = pkbf2(p1[0], p1[1]); pw1.y = pkbf2(p1[2], p1[3]);
                *(u2v*)&PF[cidx]            = pw0;
                *(u2v*)&PF[256 * 8 + cidx]  = pw1;
            }
            rsum0 += __shfl_xor(rsum0, 16);
            rsum0 += __shfl_xor(rsum0, 32);
            rs_a0 += rsum0;
            rsum1 += __shfl_xor(rsum1, 16);
            rsum1 += __shfl_xor(rsum1, 32);
            rs_a1 += rsum1;
        }
        int pidx = (iq * 64 + lm * 4 + (q4 ^ (lm & 3))) * 8;
        s8v pa0 = *(const s8v*)&PF[pidx];
        s8v pa1 = *(const s8v*)&PF[256 * 8 + pidx];

#pragma unroll
        for (int db = 0; db < 16; db++) {
            int d = db * 16 + lm;
            s8v vb = *(const s8v*)&VF[cur][(d * 4 + (q4 ^ ((d >> 1) & 3))) * 8];
            acc0[db] = __builtin_amdgcn_mfma_f32_16x16x32_bf16(pa0, vb, acc0[db], 0, 0, 0);
            acc1[db] = __builtin_amdgcn_mfma_f32_16x16x32_bf16(pa1, vb, acc1[db], 0, 0, 0);
        }
    }

    if (q4 == 0) {
        rs_s[iq * 16 + lm] = rs_a0;
        rs_s[64 + iq * 16 + lm] = rs_a1;
    }
    __syncthreads();
    if (tid < TIB)
        rsbuf[(size_t)sg * BH * Ss + (size_t)bh * Ss + I0 + tid] = rs_s[tid];

#pragma unroll
    for (int rr = 0; rr < 4; rr++) {
        float* row0 = Hdst + ((size_t)(b * Ss + I0 + iq * 16 + q4 * 4 + rr)) * Ee + hoff + lm;
        float* row1 = row0 + (size_t)64 * Ee;
#pragma unroll
        for (int db = 0; db < 16; db++) {
            row0[db * 16] = acc0[db][rr];
            row1[db * 16] = acc1[db][rr];
        }
    }
}

// ---------------------------------------------------------------------------
// Kernel 3b (fallback, inline staging, 3-barrier): kept for small workspaces.
// ---------------------------------------------------------------------------
template<int PARTS>
__global__ __launch_bounds__(256, 4) void mlstm_fallback(
    const float* __restrict__ qp, const float* __restrict__ kp, const float* __restrict__ vp,
    const float* __restrict__ a_ws, const float* __restrict__ M_ws,
    float* __restrict__ outF, float* __restrict__ Hpart, float* __restrict__ rsbuf)
{
    int bidx = blockIdx.x;
    int bh, T, sg;
    if (PARTS == 1) {
        bh = bidx & 7; T = (NT2 - 1) - (bidx >> 3); sg = 0;
    } else {
        int qd = bidx >> 8, u = bidx & 255;
        bh = u & 7;
        int r = u >> 3;
        T  = qd ? r : (31 - r);
        sg = r & 1;
    }
    int b = bh >> 2, h = bh & 3;
    int I0 = T * TI;
    int tid = threadIdx.x;

    const int tot = 2 * T + 2;
    const int jt_beg = (sg * tot) / PARTS;
    const int jt_end = ((sg + 1) * tot) / PARTS;
    const size_t hoff = (size_t)h * DHh;
    float* Hdst = (sg == 0) ? outF : (Hpart + (size_t)(sg - 1) * Bb * Ss * Ee);

    if (jt_beg >= jt_end) {
        float4 z = {0.f, 0.f, 0.f, 0.f};
        for (int t = tid; t < TI * 64; t += 256) {
            int r2 = t >> 6, c = t & 63;
            *(float4*)(Hdst + ((size_t)(b * Ss + I0 + r2)) * Ee + hoff + 4 * c) = z;
        }
        if (tid < TI) rsbuf[(size_t)sg * BH * Ss + (size_t)bh * Ss + I0 + tid] = 0.f;
        return;
    }

    __shared__ unsigned short KF[1024 * 8];
    __shared__ unsigned short VF[1024 * 8];
    __shared__ unsigned short PF[256 * 8];
    __shared__ float a_s[TJ];
    __shared__ float rs_s[TI];

    const int iq   = tid >> 6;
    const int lane = tid & 63;
    const int lm = lane & 15, q4 = lane >> 4;
    const int m5 = lane & 31, hl = lane >> 5;

    s8v qf[8];
    {
        const float* qrow = qp + ((size_t)(b * Ss + I0 + iq * 16 + lm)) * Ee + hoff;
#pragma unroll
        for (int ks = 0; ks < 8; ks++) {
            const float4* p = (const float4*)(qrow + ks * 32 + q4 * 8);
            float4 x0 = p[0], x1 = p[1];
            union { s8v v; unsigned u[4]; } rr;
            rr.u[0] = pkbf2(x0.x, x0.y);
            rr.u[1] = pkbf2(x0.z, x0.w);
            rr.u[2] = pkbf2(x1.x, x1.y);
            rr.u[3] = pkbf2(x1.z, x1.w);
            qf[ks] = rr.v;
        }
    }
    const int  i_row = I0 + iq * 16 + lm;
    const float Mi = M_ws[(size_t)bh * Ss + i_row];

    f16v acc[4];
#pragma unroll
    for (int t = 0; t < 4; t++)
#pragma unroll
        for (int i = 0; i < 16; i++) acc[t][i] = 0.f;
    float rs_acc = 0.f;

    const float inv_sqrt_dh = 0.0625f;
    const int kR  = tid >> 3, kc0 = tid & 7;
    const int vdp = tid & 127, vjb = tid >> 7;

    for (int jt = jt_beg; jt < jt_end; jt++) {
        const int J0 = jt * TJ;
        __syncthreads();
        {
            const float* src = kp + ((size_t)(b * Ss + J0 + kR)) * Ee + hoff;
#pragma unroll
            for (int p = 0; p < 4; p++) {
                int cc = kc0 + 8 * p;
                float4 x0 = ((const float4*)(src + cc * 8))[0];
                float4 x1 = ((const float4*)(src + cc * 8))[1];
                u4v wv;
                wv.x = pkbf2(x0.x, x0.y); wv.y = pkbf2(x0.z, x0.w);
                wv.z = pkbf2(x1.x, x1.y); wv.w = pkbf2(x1.z, x1.w);
                *(u4v*)&KF[(kR * 32 + (cc ^ (kR & 7))) * 8] = wv;
            }
            int d0 = vdp * 2;
#pragma unroll
            for (int p = 0; p < 2; p++) {
                int jc = vjb + 2 * p;
                const float* vbase = vp + ((size_t)(b * Ss + J0 + jc * 8)) * Ee + hoff + d0;
                float2 e0 = *(const float2*)(vbase);
                float2 e1 = *(const float2*)(vbase + Ee);
                float2 e2 = *(const float2*)(vbase + 2 * Ee);
                float2 e3 = *(const float2*)(vbase + 3 * Ee);
                float2 e4 = *(const float2*)(vbase + 4 * Ee);
                float2 e5 = *(const float2*)(vbase + 5 * Ee);
                float2 e6 = *(const float2*)(vbase + 6 * Ee);
                float2 e7 = *(const float2*)(vbase + 7 * Ee);
                int swz = jc ^ (vdp & 3);
                u4v w0, w1;
                w0.x = pkbf2(e0.x, e1.x); w0.y = pkbf2(e2.x, e3.x);
                w0.z = pkbf2(e4.x, e5.x); w0.w = pkbf2(e6.x, e7.x);
                w1.x = pkbf2(e0.y, e1.y); w1.y = pkbf2(e2.y, e3.y);
                w1.z = pkbf2(e4.y, e5.y); w1.w = pkbf2(e6.y, e7.y);
                *(u4v*)&VF[(d0 * 4 + swz) * 8] = w0;
                *(u4v*)&VF[((d0 + 1) * 4 + swz) * 8] = w1;
            }
        }
        if (tid < TJ) a_s[tid] = a_ws[(size_t)bh * Ss + J0 + tid];
        __syncthreads();

        f4v c0 = {0.f, 0.f, 0.f, 0.f}, c1 = c0;
#pragma unroll
        for (int ks = 0; ks < 8; ks++) {
            int swzk = ((ks * 4 + q4) ^ (lm & 7)) * 8;
            s8v af0 = *(const s8v*)&KF[(lm * 32) * 8 + swzk];
            s8v af1 = *(const s8v*)&KF[((16 + lm) * 32) * 8 + swzk];
            c0 = __builtin_amdgcn_mfma_f32_16x16x32_bf16(af0, qf[ks], c0, 0, 0, 0);
            c1 = __builtin_amdgcn_mfma_f32_16x16x32_bf16(af1, qf[ks], c1, 0, 0, 0);
        }
        {
            float rsum = 0.f;
#pragma unroll
            for (int t = 0; t < 2; t++) {
                const f4v cc = t ? c1 : c0;
                const int jb = t * 16 + q4 * 4;
                float p[4];
#pragma unroll
                for (int rr = 0; rr < 4; rr++) {
                    int jg = J0 + jb + rr;
                    float pv = 0.f;
                    if (jg <= i_row) pv = cc[rr] * inv_sqrt_dh * __expf(a_s[jb + rr] - Mi);
                    p[rr] = pv; rsum += pv;
                }
                u2v pwv;
                pwv.x = pkbf2(p[0], p[1]);
                pwv.y = pkbf2(p[2], p[3]);
                int i = iq * 16 + lm;
                int kb = t * 2 + (q4 >> 1);
                *(u2v*)&PF[(i * 4 + (kb ^ ((i >> 1) & 3))) * 8 + (q4 & 1) * 4] = pwv;
            }
            rsum += __shfl_xor(rsum, 16);
            rsum += __shfl_xor(rsum, 32);
            rs_acc += rsum;
        }
        __syncthreads();

#pragma unroll
        for (int ks2 = 0; ks2 < 2; ks2++) {
            int swz2 = ((ks2 * 2 + hl) ^ ((m5 >> 1) & 3)) * 8;
            s8v pa0 = *(const s8v*)&PF[(m5 * 4) * 8 + swz2];
            s8v pa1 = *(const s8v*)&PF[((32 + m5) * 4) * 8 + swz2];
            s8v vb0 = *(const s8v*)&VF[((iq * 32 + m5) * 4) * 8 + swz2];
            s8v vb1 = *(const s8v*)&VF[(((iq + 4) * 32 + m5) * 4) * 8 + swz2];
            acc[0] = __builtin_amdgcn_mfma_f32_32x32x16_bf16(pa0, vb0, acc[0], 0, 0, 0);
            acc[1] = __builtin_amdgcn_mfma_f32_32x32x16_bf16(pa0, vb1, acc[1], 0, 0, 0);
            acc[2] = __builtin_amdgcn_mfma_f32_32x32x16_bf16(pa1, vb0, acc[2], 0, 0, 0);
            acc[3] = __builtin_amdgcn_mfma_f32_32x32x16_bf16(pa1, vb1, acc[3], 0, 0, 0);
        }
    }

    if (q4 == 0) rs_s[iq * 16 + lm] = rs_acc;
    __syncthreads();
    if (tid < TI)
        rsbuf[(size_t)sg * BH * Ss + (size_t)bh * Ss + I0 + tid] = rs_s[tid];

#pragma unroll
    for (int im = 0; im < 2; im++)
#pragma unroll
        for (int ns = 0; ns < 2; ns++) {
            const f16v av = acc[im * 2 + ns];
            const int col = (iq + 4 * ns) * 32 + m5;
#pragma unroll
            for (int rr = 0; rr < 16; rr++) {
                int row = I0 + im * 32 + (rr & 3) + 8 * (rr >> 2) + 4 * hl;
                Hdst[((size_t)(b * Ss + row)) * Ee + hoff + col] = av[rr];
            }
        }
}

// ---------------------------------------------------------------------------
// Kernel 4a: combine for the chunked mapping. Per row: TI=64 tile T occupies
// global iters [T(T+1), T(T+1)+2T+2); piece count p = (chunks intersecting)
// = (tend-1)/11 - tstart/11 + 1. Same closed form as the mlstm kernel's ord.
// ---------------------------------------------------------------------------
__global__ __launch_bounds__(256) void combine_ch(
    const float* __restrict__ Hb, const float* __restrict__ rsbuf,
    const float* __restrict__ nf_ws, const float* __restrict__ out_w,
    float* __restrict__ outF)
{
    int rid = blockIdx.x * 4 + (threadIdx.x >> 6);
    int lane = threadIdx.x & 63;
    int bh = rid >> 11, s = rid & 2047;
    int b = bh >> 2, h = bh & 3;
    int T = s >> 6;                      // TI=64 tile index
    int tstart = T * (T + 1);
    int tend   = tstart + 2 * T + 2;
    int p = (tend - 1) / 11 - tstart / 11 + 1;

    size_t base = ((size_t)(b * Ss + s)) * Ee + (size_t)h * DHh + lane * 4;
    const size_t HP = (size_t)Bb * Ss * Ee;
    float4 ha = *(const float4*)(outF + base);
    float rs = rsbuf[(size_t)bh * Ss + s];
    for (int k = 1; k < p; k++) {
        float4 hb = *(const float4*)(Hb + (size_t)(k - 1) * HP + base);
        ha.x += hb.x; ha.y += hb.y; ha.z += hb.z; ha.w += hb.w;
        rs += rsbuf[(size_t)k * BH * Ss + (size_t)bh * Ss + s];
    }
    float nfv = nf_ws[(size_t)bh * Ss + s];
    float invn = 1.f / (fmaxf(fabsf(rs), nfv) + 1e-8f);
    float4 x;
    x.x = ha.x * invn; x.y = ha.y * invn; x.z = ha.z * invn; x.w = ha.w * invn;
    float sx = x.x + x.y + x.z + x.w;
    float sq = x.x*x.x + x.y*x.y + x.z*x.z + x.w*x.w;
#pragma unroll
    for (int off = 1; off < 64; off <<= 1) {
        sx += __shfl_xor(sx, off);
        sq += __shfl_xor(sq, off);
    }
    float mean = sx * (1.f / DHh);
    float var  = sq * (1.f / DHh) - mean * mean;
    float rstd = rsqrtf(var + 1e-5f);
    float4 w4 = *(const float4*)(out_w + (size_t)h * DHh + lane * 4);
    float4 o;
    o.x = (x.x - mean) * rstd * (1.f + w4.x);
    o.y = (x.y - mean) * rstd * (1.f + w4.y);
    o.z = (x.z - mean) * rstd * (1.f + w4.z);
    o.w = (x.w - mean) * rstd * (1.f + w4.w);
    *(float4*)(outF + base) = o;
}

// ---------------------------------------------------------------------------
// Kernel 4b: fixed-PARTS combine (for big2 path and fallbacks).
// ---------------------------------------------------------------------------
template<int PARTS>
__global__ __launch_bounds__(256) void combine_kernel(
    const float* __restrict__ Hb, const float* __restrict__ rsbuf,
    const float* __restrict__ nf_ws, const float* __restrict__ out_w,
    float* __restrict__ outF)
{
    int rid = blockIdx.x * 4 + (threadIdx.x >> 6);
    int lane = threadIdx.x & 63;
    int bh = rid >> 11, s = rid & 2047;
    int b = bh >> 2, h = bh & 3;
    size_t base = ((size_t)(b * Ss + s)) * Ee + (size_t)h * DHh + lane * 4;
    float4 ha = *(const float4*)(outF + base);
    float rs = rsbuf[(size_t)bh * Ss + s];
#pragma unroll
    for (int k = 1; k < PARTS; k++) {
        float4 hb = *(const float4*)(Hb + (size_t)(k - 1) * Bb * Ss * Ee + base);
        ha.x += hb.x; ha.y += hb.y; ha.z += hb.z; ha.w += hb.w;
        rs += rsbuf[(size_t)k * BH * Ss + (size_t)bh * Ss + s];
    }
    float nfv = nf_ws[(size_t)bh * Ss + s];
    float invn = 1.f / (fmaxf(fabsf(rs), nfv) + 1e-8f);
    float4 x;
    x.x = ha.x * invn; x.y = ha.y * invn; x.z = ha.z * invn; x.w = ha.w * invn;
    float sx = x.x + x.y + x.z + x.w;
    float sq = x.x*x.x + x.y*x.y + x.z*x.z + x.w*x.w;
#pragma unroll
    for (int off = 1; off < 64; off <<= 1) {
        sx += __shfl_xor(sx, off);
        sq += __shfl_xor(sq, off);
    }
    float mean = sx * (1.f / DHh);
    float var  = sq * (1.f / DHh) - mean * mean;
    float rstd = rsqrtf(var + 1e-5f);
    float4 w4 = *(const float4*)(out_w + (size_t)h * DHh + lane * 4);
    float4 o;
    o.x = (x.x - mean) * rstd * (1.f + w4.x);
    o.y = (x.y - mean) * rstd * (1.f + w4.y);
    o.z = (x.z - mean) * rstd * (1.f + w4.z);
    o.w = (x.w - mean) * rstd * (1.f + w4.w);
    *(float4*)(outF + base) = o;
}

// ---------------------------------------------------------------------------
extern "C" void kernel_launch(void* const* d_in, const int* in_sizes, int n_in,
                              void* d_out, int out_size, void* d_ws, size_t ws_size,
                              hipStream_t stream) {
    const float* q   = (const float*)d_in[0];
    const float* k   = (const float*)d_in[1];
    const float* v   = (const float*)d_in[2];
    const float* igw = (const float*)d_in[3];
    const float* igb = (const float*)d_in[4];
    const float* fgw = (const float*)d_in[5];
    const float* fgb = (const float*)d_in[6];
    const float* ow  = (const float*)d_in[7];
    float* out = (float*)d_out;

    float* ws = (float*)d_ws;
    float* ig = ws;                     // BH*S floats each
    float* fg = ws + 16384;
    float* aa = ws + 32768;
    float* MM = ws + 49152;
    float* nf = ws + 65536;
    float* rsb = ws + 81920;            // 8 slots x BH*S = 131072 floats
    const size_t base_f = 81920 + 131072;           // 212992 floats
    unsigned short* KimgP = (unsigned short*)(ws + base_f);
    const size_t img_u = (size_t)BH * NJT * 1024 * 8;        // 8.4 MB each (u16)
    unsigned short* VimgP = KimgP + img_u;
    float* HpartImg = (float*)(VimgP + img_u);
    float* HpartRaw = ws + base_f;
    const size_t HP = (size_t)Bb * Ss * Ee;                  // 16.8 MB

    const size_t need_ch = base_f * 4 + 2 * img_u * 2 + 6 * HP * 4;  // ~118 MB
    const size_t need4   = base_f * 4 + 2 * img_u * 2 + 3 * HP * 4;  // ~85 MB
    const size_t need2   = base_f * 4 + 1 * HP * 4;

    if (ws_size >= need_ch) {
        gates_prep_kernel<<<1024, 256, 0, stream>>>(q, k, v, igw, igb, fgw, fgb,
                                                    ig, fg, KimgP, VimgP);
        scan_kernel<<<BH, 256, 0, stream>>>(ig, fg, aa, MM, nf);
        mlstm_ch<<<768, 256, 0, stream>>>(q, KimgP, VimgP, aa, MM,
                                          out, HpartImg, rsb);
        combine_ch<<<BH * Ss / 4, 256, 0, stream>>>(HpartImg, rsb, nf, ow, out);
    } else if (ws_size >= need4) {
        gates_prep_kernel<<<1024, 256, 0, stream>>>(q, k, v, igw, igb, fgw, fgb,
                                                    ig, fg, KimgP, VimgP);
        scan_kernel<<<BH, 256, 0, stream>>>(ig, fg, aa, MM, nf);
        mlstm_big2<<<512, 256, 0, stream>>>(q, KimgP, VimgP, aa, MM,
                                            out, HpartImg, rsb);
        combine_kernel<4><<<BH * Ss / 4, 256, 0, stream>>>(HpartImg, rsb, nf, ow, out);
    } else if (ws_size >= need2) {
        gates_prep_kernel<<<512, 256, 0, stream>>>(q, k, v, igw, igb, fgw, fgb,
                                                   ig, fg, nullptr, nullptr);
        scan_kernel<<<BH, 256, 0, stream>>>(ig, fg, aa, MM, nf);
        mlstm_fallback<2><<<512, 256, 0, stream>>>(q, k, v, aa, MM, out, HpartRaw, rsb);
        combine_kernel<2><<<BH * Ss / 4, 256, 0, stream>>>(HpartRaw, rsb, nf, ow, out);
    } else {
        gates_prep_kernel<<<512, 256, 0, stream>>>(q, k, v, igw, igb, fgw, fgb,
                                                   ig, fg, nullptr, nullptr);
        scan_kernel<<<BH, 256, 0, stream>>>(ig, fg, aa, MM, nf);
        mlstm_fallback<1><<<256, 256, 0, stream>>>(q, k, v, aa, MM, out, HpartRaw, rsb);
        combine_kernel<1><<<BH * Ss / 4, 256, 0, stream>>>(HpartRaw, rsb, nf, ow, out);
    }
}

// Round 12
// 185.222 us; speedup vs baseline: 1.0484x; 1.0070x over previous
//
#include <hip/hip_runtime.h>
#include <hip/hip_bf16.h>
#include <math.h>

// Problem constants: B=2, S=2048, E=1024, NH=4, DH=256
#define Bb  2
#define Ss  2048
#define Ee  1024
#define NHh 4
#define DHh 256
#define BH  (Bb*NHh)      // 8
#define TI  64            // i-rows per tile (main + fallback)
#define TIB 128           // i-rows per block (big2 fallback path)
#define TJ  32            // j-cols per iteration
#define NT2 (Ss/TI)       // 32 i-tiles per bh
#define NJT (Ss/TJ)       // 64 j-tiles per bh

typedef short        s8v   __attribute__((ext_vector_type(8)));   // 8 bf16 (A/B frag)
typedef float        f4v   __attribute__((ext_vector_type(4)));   // 16x16 acc
typedef float        f16v  __attribute__((ext_vector_type(16)));  // 32x32 acc
typedef unsigned int u4v   __attribute__((ext_vector_type(4)));   // 16B LDS write
typedef unsigned int u2v   __attribute__((ext_vector_type(2)));   // 8B LDS write

// fp32 pair -> packed bf16x2 via HW v_cvt_pk_bf16_f32 (a = low 16)
__device__ inline unsigned pkbf2(float a, float b) {
    __hip_bfloat162 h2 = __float22bfloat162_rn(float2{a, b});
    unsigned u;
    __builtin_memcpy(&u, &h2, 4);
    return u;
}

// async 16B global->LDS DMA; lds arg must be wave-uniform (HW adds lane*16)
__device__ inline void async16(const void* g, void* l) {
    __builtin_amdgcn_global_load_lds(
        (const __attribute__((address_space(1))) void*)g,
        (__attribute__((address_space(3))) void*)l, 16, 0, 0);
}

// ---------------------------------------------------------------------------
// Kernel 1 (fused, r6-champion + prefetch): blocks 0..511 = gates (weights
// LDS-staged, 16 rows x 2 heads each, 2 rows per barrier-pair, NEXT row-pair
// loads issued before the current reduce/barriers so L3 latency hides under
// the shfl ladder); blocks 512..1023 = prep (K/V -> swizzled bf16 images).
// ---------------------------------------------------------------------------
__global__ __launch_bounds__(256) void gates_prep_kernel(
    const float* __restrict__ q, const float* __restrict__ k, const float* __restrict__ v,
    const float* __restrict__ igw, const float* __restrict__ igb,
    const float* __restrict__ fgw, const float* __restrict__ fgb,
    float* __restrict__ ig_out, float* __restrict__ fg_out,
    unsigned short* __restrict__ Kimg, unsigned short* __restrict__ Vimg)
{
    int bidx = blockIdx.x;
    int tid = threadIdx.x;

    if (bidx >= 512) {               // ---------------- prep path ----------------
        int pidx = bidx - 512;       // bh*NJT + jt
        int bh = pidx >> 6, jt = pidx & 63;
        int b = bh >> 2, h = bh & 3;
        int J0 = jt * TJ;
        const size_t hoff = (size_t)h * DHh;
        unsigned short* Kt = Kimg + (size_t)pidx * 1024 * 8;
        unsigned short* Vt = Vimg + (size_t)pidx * 1024 * 8;

        // K: chunk(kR,cc) at kR*32 + (cc ^ (kR&7)), holds K[J0+kR][cc*8..+7]
        {
            int kR = tid >> 3, kc0 = tid & 7;
            const float* src = k + ((size_t)(b * Ss + J0 + kR)) * Ee + hoff;
#pragma unroll
            for (int p = 0; p < 4; p++) {
                int cc = kc0 + 8 * p;
                float4 x0 = ((const float4*)(src + cc * 8))[0];
                float4 x1 = ((const float4*)(src + cc * 8))[1];
                u4v wv;
                wv.x = pkbf2(x0.x, x0.y); wv.y = pkbf2(x0.z, x0.w);
                wv.z = pkbf2(x1.x, x1.y); wv.w = pkbf2(x1.z, x1.w);
                *(u4v*)&Kt[(kR * 32 + (cc ^ (kR & 7))) * 8] = wv;
            }
        }
        // V^T: chunk(d,jc) at d*4 + (jc ^ ((d>>1)&3)), holds V[J0+jc*8+e][d]
        {
            int vdp = tid & 127, vjb = tid >> 7;
            int d0 = vdp * 2;
#pragma unroll
            for (int p = 0; p < 2; p++) {
                int jc = vjb + 2 * p;
                const float* vbase = v + ((size_t)(b * Ss + J0 + jc * 8)) * Ee + hoff + d0;
                float2 e0 = *(const float2*)(vbase);
                float2 e1 = *(const float2*)(vbase + Ee);
                float2 e2 = *(const float2*)(vbase + 2 * Ee);
                float2 e3 = *(const float2*)(vbase + 3 * Ee);
                float2 e4 = *(const float2*)(vbase + 4 * Ee);
                float2 e5 = *(const float2*)(vbase + 5 * Ee);
                float2 e6 = *(const float2*)(vbase + 6 * Ee);
                float2 e7 = *(const float2*)(vbase + 7 * Ee);
                int swz = jc ^ (vdp & 3);
                u4v w0, w1;
                w0.x = pkbf2(e0.x, e1.x); w0.y = pkbf2(e2.x, e3.x);
                w0.z = pkbf2(e4.x, e5.x); w0.w = pkbf2(e6.x, e7.x);
                w1.x = pkbf2(e0.y, e1.y); w1.y = pkbf2(e2.y, e3.y);
                w1.z = pkbf2(e4.y, e5.y); w1.w = pkbf2(e6.y, e7.y);
                *(u4v*)&Vt[(d0 * 4 + swz) * 8] = w0;
                *(u4v*)&Vt[((d0 + 1) * 4 + swz) * 8] = w1;
            }
        }
        return;
    }

    // ---------------- gates path: 2 rows per barrier-pair, prefetched ----------
    int sc = bidx >> 1, hp = bidx & 1;
    __shared__ float wl[4][3072];          // 48 KB
    __shared__ float pw[4][8];

#pragma unroll
    for (int c = 0; c < 4; c++) {
        int h = hp * 2 + (c >> 1);
        const float* src = ((c & 1) ? fgw : igw) + (size_t)h * 3 * Ee;
        for (int idx = tid * 4; idx < 3 * Ee; idx += 1024)
            *(float4*)&wl[c][idx] = *(const float4*)(src + idx);
    }
    __syncthreads();

    int c4 = tid * 4;
    int w = tid >> 6, lane = tid & 63;

    // prefetch sp=0 rows
    int bs0 = sc * 16;
    float4 qa = *(const float4*)(q + (size_t)bs0 * Ee + c4);
    float4 ka = *(const float4*)(k + (size_t)bs0 * Ee + c4);
    float4 va = *(const float4*)(v + (size_t)bs0 * Ee + c4);
    float4 qb = *(const float4*)(q + (size_t)(bs0 + 1) * Ee + c4);
    float4 kb = *(const float4*)(k + (size_t)(bs0 + 1) * Ee + c4);
    float4 vb = *(const float4*)(v + (size_t)(bs0 + 1) * Ee + c4);

    for (int sp = 0; sp < 8; sp++) {
        bs0 = sc * 16 + sp * 2;
        // issue next row-pair loads NOW; they complete under this sp's
        // reduce + barriers (compiler can't hoist loads across syncthreads)
        float4 nqa, nka, nva, nqb, nkb, nvb;
        if (sp < 7) {
            int nbs = bs0 + 2;
            nqa = *(const float4*)(q + (size_t)nbs * Ee + c4);
            nka = *(const float4*)(k + (size_t)nbs * Ee + c4);
            nva = *(const float4*)(v + (size_t)nbs * Ee + c4);
            nqb = *(const float4*)(q + (size_t)(nbs + 1) * Ee + c4);
            nkb = *(const float4*)(k + (size_t)(nbs + 1) * Ee + c4);
            nvb = *(const float4*)(v + (size_t)(nbs + 1) * Ee + c4);
        }
        float red[8];
#pragma unroll
        for (int c = 0; c < 4; c++) {
            const float* wc = wl[c];
            float4 wq = *(const float4*)&wc[c4];
            float4 wk = *(const float4*)&wc[Ee + c4];
            float4 wv = *(const float4*)&wc[2 * Ee + c4];
            float x0 = qa.x*wq.x + qa.y*wq.y + qa.z*wq.z + qa.w*wq.w
                     + ka.x*wk.x + ka.y*wk.y + ka.z*wk.z + ka.w*wk.w
                     + va.x*wv.x + va.y*wv.y + va.z*wv.z + va.w*wv.w;
            float x1 = qb.x*wq.x + qb.y*wq.y + qb.z*wq.z + qb.w*wq.w
                     + kb.x*wk.x + kb.y*wk.y + kb.z*wk.z + kb.w*wk.w
                     + vb.x*wv.x + vb.y*wv.y + vb.z*wv.z + vb.w*wv.w;
            for (int off = 32; off > 0; off >>= 1) {
                x0 += __shfl_down(x0, off, 64);
                x1 += __shfl_down(x1, off, 64);
            }
            red[c] = x0; red[4 + c] = x1;
        }
        __syncthreads();
        if (lane == 0) {
#pragma unroll
            for (int c = 0; c < 8; c++) pw[w][c] = red[c];
        }
        __syncthreads();
        if (tid < 8) {
            float t = pw[0][tid] + pw[1][tid] + pw[2][tid] + pw[3][tid];
            int rr = tid >> 2, cc = tid & 3;
            int h = hp * 2 + (cc >> 1);
            int bs = bs0 + rr;
            int b = bs >> 11, s = bs & 2047;
            size_t o = ((size_t)(b * NHh + h)) * Ss + s;
            if (cc & 1) fg_out[o] = t + fgb[h];
            else        ig_out[o] = t + igb[h];
        }
        if (sp < 7) {
            qa = nqa; ka = nka; va = nva;
            qb = nqb; kb = nkb; vb = nvb;
        }
    }
}

// ---------------------------------------------------------------------------
// Kernel 2: per-(b,h) scan, wave-shuffle version (8 blocks, 2 barriers;
// verified r9/r10/r11).
// ---------------------------------------------------------------------------
#define CHUNK 8
__global__ __launch_bounds__(256) void scan_kernel(
    const float* __restrict__ ig, const float* __restrict__ fg,
    float* __restrict__ a_out, float* __restrict__ M_out, float* __restrict__ nf_out)
{
    int bh = blockIdx.x;
    int tid = threadIdx.x;
    const float* igp = ig + (size_t)bh * Ss;
    const float* fgp = fg + (size_t)bh * Ss;
    int s0 = tid * CHUNK;
    int lane = tid & 63, wv = tid >> 6;

    float ls[CHUNK], cs[CHUNK];
    float tot = 0.f;
#pragma unroll
    for (int c = 0; c < CHUNK; c++) {
        float x = fgp[s0 + c];
        float l = fminf(x, 0.f) - log1pf(expf(-fabsf(x)));
        ls[c] = l; tot += l; cs[c] = tot;
    }
    // inclusive wave scan of tot
    float xs = tot;
#pragma unroll
    for (int off = 1; off < 64; off <<= 1) {
        float y = __shfl_up(xs, off, 64);
        if (lane >= off) xs += y;
    }
    __shared__ float wsum[4];
    if (lane == 63) wsum[wv] = xs;
    __syncthreads();
    float wpre = 0.f;
    for (int i = 0; i < wv; i++) wpre += wsum[i];
    float excl = wpre + xs - tot;      // exclusive prefix over threads

    float av[CHUNK], pmax[CHUNK];
    float tmax = -INFINITY;
#pragma unroll
    for (int c = 0; c < CHUNK; c++) {
        float csf  = excl + cs[c];
        float csm1 = csf - ls[c];
        float a = igp[s0 + c] - csm1;
        av[c] = a;
        tmax = fmaxf(tmax, a);
        pmax[c] = tmax;
        cs[c] = csf;
    }
    // inclusive wave max-scan of tmax
    float xm = tmax;
#pragma unroll
    for (int off = 1; off < 64; off <<= 1) {
        float y = __shfl_up(xm, off, 64);
        if (lane >= off) xm = fmaxf(xm, y);
    }
    __shared__ float wmax[4];
    if (lane == 63) wmax[wv] = xm;
    __syncthreads();
    float mpre = -INFINITY;
    for (int i = 0; i < wv; i++) mpre = fmaxf(mpre, wmax[i]);
    float me = __shfl_up(xm, 1, 64);
    if (lane == 0) me = -INFINITY;
    float emax = fmaxf(mpre, me);

#pragma unroll
    for (int c = 0; c < CHUNK; c++) {
        float M = fmaxf(emax, pmax[c]);
        size_t o = (size_t)bh * Ss + s0 + c;
        a_out[o]  = av[c];
        M_out[o]  = M;
        nf_out[o] = expf(-cs[c] - M);
    }
}

// ---------------------------------------------------------------------------
// Kernel 3 (main path, stable 57-61us): 12-wave equal-work residency.
// 1056 iters/bh = 96 chunks x 11 exactly; 768 blocks, 3/CU, zero imbalance.
// ---------------------------------------------------------------------------
__global__ __launch_bounds__(256, 3) void mlstm_ch(
    const float* __restrict__ qp,
    const unsigned short* __restrict__ Kimg, const unsigned short* __restrict__ Vimg,
    const float* __restrict__ a_ws, const float* __restrict__ M_ws,
    float* __restrict__ outF, float* __restrict__ Hpart, float* __restrict__ rsbuf)
{
    int bidx = blockIdx.x;           // 0..767
    int bh = bidx & 7;
    int c  = bidx >> 3;              // chunk 0..95
    int b = bh >> 2, h = bh & 3;
    int tid = threadIdx.x;

    const size_t hoff = (size_t)h * DHh;
    const size_t HP = (size_t)Bb * Ss * Ee;

    __shared__ unsigned short KF[1024 * 8];      // 16 KB (single buffer)
    __shared__ unsigned short VF[1024 * 8];      // 16 KB (single buffer)
    __shared__ unsigned short PF[256 * 8];       // 4 KB (wave-private quarters)
    __shared__ float a_s[TJ];
    __shared__ float rs_s[TI];

    const int iq   = tid >> 6;       // wave id (0..3)
    const int lane = tid & 63;
    const int lm = lane & 15, q4 = lane >> 4;
    const float inv_sqrt_dh = 0.0625f;

    const unsigned short* Kb = Kimg + (size_t)(bh * NJT) * 1024 * 8;
    const unsigned short* Vb = Vimg + (size_t)(bh * NJT) * 1024 * 8;
    const float* a_base = a_ws + (size_t)bh * Ss;

    int g    = c * 11;               // global iter in [0,1056)
    int gend = g + 11;
    // tile containing g: T(T+1) <= g < (T+1)(T+2)
    int T = (int)((sqrtf((float)(4 * g + 1)) - 1.f) * 0.5f);
    while (T * (T + 1) > g) T--;
    while ((T + 1) * (T + 2) <= g) T++;

    while (g < gend) {
        const int tstart = T * (T + 1);
        const int tend   = tstart + 2 * T + 2;
        const int jt_beg = g - tstart;
        const int pend   = (gend < tend) ? gend : tend;
        const int jt_end = pend - tstart;
        const int ord    = c - tstart / 11;     // chunk rank within this tile
        const int I0     = T * TI;
        float* Hdst = (ord == 0) ? outF : (Hpart + (size_t)(ord - 1) * HP);

        // ---- Q fragments in registers (B-operand of S^T = K·Q^T) ----
        s8v qf[8];
        {
            const float* qrow = qp + ((size_t)(b * Ss + I0 + iq * 16 + lm)) * Ee + hoff;
#pragma unroll
            for (int ks = 0; ks < 8; ks++) {
                const float4* p = (const float4*)(qrow + ks * 32 + q4 * 8);
                float4 x0 = p[0], x1 = p[1];
                union { s8v v; unsigned u[4]; } rr;
                rr.u[0] = pkbf2(x0.x, x0.y);
                rr.u[1] = pkbf2(x0.z, x0.w);
                rr.u[2] = pkbf2(x1.x, x1.y);
                rr.u[3] = pkbf2(x1.z, x1.w);
                qf[ks] = rr.v;
            }
        }
        const int  i_row = I0 + iq * 16 + lm;
        const float Mi = M_ws[(size_t)bh * Ss + i_row];

        f4v acc[16];                 // H[i=iq*16+q4*4+rr][d=db*16+lm]
#pragma unroll
        for (int t = 0; t < 16; t++) { acc[t][0]=0.f; acc[t][1]=0.f; acc[t][2]=0.f; acc[t][3]=0.f; }
        float rs_acc = 0.f;

        // piece prologue: K(jt_beg) + a(jt_beg)
        {
            const unsigned short* Kt = Kb + (size_t)jt_beg * 1024 * 8;
#pragma unroll
            for (int p = 0; p < 4; p++) {
                int cbase = (iq * 4 + p) * 64;
                async16(Kt + (size_t)(cbase + lane) * 8, &KF[cbase * 8]);
            }
            if (lane < 2)
                async16(a_base + (size_t)jt_beg * TJ + iq * 8 + lane * 4, &a_s[iq * 8]);
        }
        __syncthreads();   // K+a landed; prev piece's VF reads / rs_s use done

        for (int jt = jt_beg; jt < jt_end; jt++) {
            // issue V(jt) -> VF; lands under the QK phase
            {
                const unsigned short* Vt = Vb + (size_t)jt * 1024 * 8;
#pragma unroll
                for (int p = 0; p < 4; p++) {
                    int cbase = (iq * 4 + p) * 64;
                    async16(Vt + (size_t)(cbase + lane) * 8, &VF[cbase * 8]);
                }
            }
            const int J0 = jt * TJ;

            // ---- QK: S^T [32j x 16i] per wave via mfma 16x16x32 ----
            f4v c0 = {0.f, 0.f, 0.f, 0.f}, c1 = c0;
            __builtin_amdgcn_s_setprio(1);
#pragma unroll
            for (int ks = 0; ks < 8; ks++) {
                int swzk = ((ks * 4 + q4) ^ (lm & 7)) * 8;
                s8v af0 = *(const s8v*)&KF[(lm * 32) * 8 + swzk];
                s8v af1 = *(const s8v*)&KF[((16 + lm) * 32) * 8 + swzk];
                c0 = __builtin_amdgcn_mfma_f32_16x16x32_bf16(af0, qf[ks], c0, 0, 0, 0);
                c1 = __builtin_amdgcn_mfma_f32_16x16x32_bf16(af1, qf[ks], c1, 0, 0, 0);
            }
            __builtin_amdgcn_s_setprio(0);
            // decay + mask + rowsum + pack P into wave-private PF quarter
            {
                float rsum = 0.f;
#pragma unroll
                for (int t = 0; t < 2; t++) {
                    const f4v cc = t ? c1 : c0;
                    const int jb = t * 16 + q4 * 4;
                    float p[4];
#pragma unroll
                    for (int rr = 0; rr < 4; rr++) {
                        int jg = J0 + jb + rr;
                        float pv = 0.f;
                        if (jg <= i_row) pv = cc[rr] * inv_sqrt_dh * __expf(a_s[jb + rr] - Mi);
                        p[rr] = pv; rsum += pv;
                    }
                    u2v pwv;
                    pwv.x = pkbf2(p[0], p[1]);
                    pwv.y = pkbf2(p[2], p[3]);
                    int kb = t * 2 + (q4 >> 1);
                    *(u2v*)&PF[(iq * 64 + lm * 4 + (kb ^ (lm & 3))) * 8 + (q4 & 1) * 4] = pwv;
                }
                rsum += __shfl_xor(rsum, 16);
                rsum += __shfl_xor(rsum, 32);
                rs_acc += rsum;
            }
            // wave-private PF read-back in A-frag order (lgkmcnt-ordered)
            s8v pa = *(const s8v*)&PF[(iq * 64 + lm * 4 + (q4 ^ (lm & 3))) * 8];

            __syncthreads();   // V(jt) landed; all waves done reading KF(jt)

            // issue K(jt+1)+a(jt+1) -> KF; lands under the PV phase
            if (jt + 1 < jt_end) {
                const unsigned short* Kt = Kb + (size_t)(jt + 1) * 1024 * 8;
#pragma unroll
                for (int p = 0; p < 4; p++) {
                    int cbase = (iq * 4 + p) * 64;
                    async16(Kt + (size_t)(cbase + lane) * 8, &KF[cbase * 8]);
                }
                if (lane < 2)
                    async16(a_base + (size_t)(jt + 1) * TJ + iq * 8 + lane * 4, &a_s[iq * 8]);
            }

            // ---- PV: H[16i x 256d] += P[16x32] · V[32x256] ----
            __builtin_amdgcn_s_setprio(1);
#pragma unroll
            for (int db = 0; db < 16; db++) {
                int d = db * 16 + lm;
                s8v vb = *(const s8v*)&VF[(d * 4 + (q4 ^ ((d >> 1) & 3))) * 8];
                acc[db] = __builtin_amdgcn_mfma_f32_16x16x32_bf16(pa, vb, acc[db], 0, 0, 0);
            }
            __builtin_amdgcn_s_setprio(0);

            __syncthreads();   // K(jt+1)+a landed; all waves done reading VF(jt)
        }

        // ---- piece epilogue: rowsums + raw fp32 partial H ----
        if (q4 == 0) rs_s[iq * 16 + lm] = rs_acc;
        __syncthreads();
        if (tid < TI)
            rsbuf[(size_t)ord * BH * Ss + (size_t)bh * Ss + I0 + tid] = rs_s[tid];

#pragma unroll
        for (int rr = 0; rr < 4; rr++) {
            float* row = Hdst + ((size_t)(b * Ss + I0 + iq * 16 + q4 * 4 + rr)) * Ee + hoff + lm;
#pragma unroll
            for (int db = 0; db < 16; db++)
                row[db * 16] = acc[db][rr];
        }

        g = pend;
        if (g >= tend) T++;
    }
}

// ---------------------------------------------------------------------------
// Kernel 3-alt (r3-proven path for 3-slab workspaces): dual-row-set dbuf.
// ---------------------------------------------------------------------------
__global__ __launch_bounds__(256, 2) void mlstm_big2(
    const float* __restrict__ qp,
    const unsigned short* __restrict__ Kimg, const unsigned short* __restrict__ Vimg,
    const float* __restrict__ a_ws, const float* __restrict__ M_ws,
    float* __restrict__ outF, float* __restrict__ Hpart, float* __restrict__ rsbuf)
{
    int bidx = blockIdx.x;
    int qd = bidx >> 7, u = bidx & 127;
    int bh = u & 7;
    int r  = u >> 3;                 // 0..15
    int T  = (qd < 2) ? (15 - r) : r;
    int sg = qd;
    int b = bh >> 2, h = bh & 3;
    int I0 = T * TIB;
    int tid = threadIdx.x;

    const int tot = 4 * T + 4;
    const int jt_beg = (sg * tot) / 4;
    const int jt_end = ((sg + 1) * tot) / 4;
    const size_t hoff = (size_t)h * DHh;
    float* Hdst = (sg == 0) ? outF : (Hpart + (size_t)(sg - 1) * Bb * Ss * Ee);

    __shared__ unsigned short KF[2][1024 * 8];
    __shared__ unsigned short VF[2][1024 * 8];
    __shared__ unsigned short PF[512 * 8];
    __shared__ float a_s[2][TJ];
    __shared__ float rs_s[TIB];

    const int iq   = tid >> 6;
    const int lane = tid & 63;
    const int lm = lane & 15, q4 = lane >> 4;

    s8v qf0[8], qf1[8];
    {
        const float* qrow0 = qp + ((size_t)(b * Ss + I0 + iq * 16 + lm)) * Ee + hoff;
        const float* qrow1 = qrow0 + (size_t)64 * Ee;
#pragma unroll
        for (int ks = 0; ks < 8; ks++) {
            const float4* p0 = (const float4*)(qrow0 + ks * 32 + q4 * 8);
            float4 x0 = p0[0], x1 = p0[1];
            union { s8v v; unsigned u[4]; } rr;
            rr.u[0] = pkbf2(x0.x, x0.y);
            rr.u[1] = pkbf2(x0.z, x0.w);
            rr.u[2] = pkbf2(x1.x, x1.y);
            rr.u[3] = pkbf2(x1.z, x1.w);
            qf0[ks] = rr.v;
            const float4* p1 = (const float4*)(qrow1 + ks * 32 + q4 * 8);
            float4 y0 = p1[0], y1 = p1[1];
            union { s8v v; unsigned u[4]; } ss;
            ss.u[0] = pkbf2(y0.x, y0.y);
            ss.u[1] = pkbf2(y0.z, y0.w);
            ss.u[2] = pkbf2(y1.x, y1.y);
            ss.u[3] = pkbf2(y1.z, y1.w);
            qf1[ks] = ss.v;
        }
    }
    const int  i_row0 = I0 + iq * 16 + lm;
    const int  i_row1 = i_row0 + 64;
    const float Mi0 = M_ws[(size_t)bh * Ss + i_row0];
    const float Mi1 = M_ws[(size_t)bh * Ss + i_row1];

    f4v acc0[16], acc1[16];
#pragma unroll
    for (int t = 0; t < 16; t++) {
        acc0[t][0]=0.f; acc0[t][1]=0.f; acc0[t][2]=0.f; acc0[t][3]=0.f;
        acc1[t][0]=0.f; acc1[t][1]=0.f; acc1[t][2]=0.f; acc1[t][3]=0.f;
    }
    float rs_a0 = 0.f, rs_a1 = 0.f;
    const float inv_sqrt_dh = 0.0625f;

    const unsigned short* Kb = Kimg + (size_t)(bh * NJT) * 1024 * 8;
    const unsigned short* Vb = Vimg + (size_t)(bh * NJT) * 1024 * 8;

    {
        const unsigned short* Kt = Kb + (size_t)jt_beg * 1024 * 8;
        const unsigned short* Vt = Vb + (size_t)jt_beg * 1024 * 8;
#pragma unroll
        for (int p = 0; p < 4; p++) {
            int cbase = (iq * 4 + p) * 64;
            async16(Kt + (size_t)(cbase + lane) * 8, &KF[0][cbase * 8]);
            async16(Vt + (size_t)(cbase + lane) * 8, &VF[0][cbase * 8]);
        }
        if (tid < TJ) a_s[0][tid] = a_ws[(size_t)bh * Ss + jt_beg * TJ + tid];
    }

    int cur = 0;
    for (int jt = jt_beg; jt < jt_end; jt++, cur ^= 1) {
        __syncthreads();

        if (jt + 1 < jt_end) {
            const unsigned short* Kt = Kb + (size_t)(jt + 1) * 1024 * 8;
            const unsigned short* Vt = Vb + (size_t)(jt + 1) * 1024 * 8;
#pragma unroll
            for (int p = 0; p < 4; p++) {
                int cbase = (iq * 4 + p) * 64;
                async16(Kt + (size_t)(cbase + lane) * 8, &KF[cur ^ 1][cbase * 8]);
                async16(Vt + (size_t)(cbase + lane) * 8, &VF[cur ^ 1][cbase * 8]);
            }
            if (tid < TJ) a_s[cur ^ 1][tid] = a_ws[(size_t)bh * Ss + (jt + 1) * TJ + tid];
        }
        const int J0 = jt * TJ;

        f4v c00 = {0.f,0.f,0.f,0.f}, c01 = c00, c10 = c00, c11 = c00;
#pragma unroll
        for (int ks = 0; ks < 8; ks++) {
            int swzk = ((ks * 4 + q4) ^ (lm & 7)) * 8;
            s8v af0 = *(const s8v*)&KF[cur][(lm * 32) * 8 + swzk];
            s8v af1 = *(const s8v*)&KF[cur][((16 + lm) * 32) * 8 + swzk];
            c00 = __builtin_amdgcn_mfma_f32_16x16x32_bf16(af0, qf0[ks], c00, 0, 0, 0);
            c01 = __builtin_amdgcn_mfma_f32_16x16x32_bf16(af1, qf0[ks], c01, 0, 0, 0);
            c10 = __builtin_amdgcn_mfma_f32_16x16x32_bf16(af0, qf1[ks], c10, 0, 0, 0);
            c11 = __builtin_amdgcn_mfma_f32_16x16x32_bf16(af1, qf1[ks], c11, 0, 0, 0);
        }
        {
            float rsum0 = 0.f, rsum1 = 0.f;
#pragma unroll
            for (int t = 0; t < 2; t++) {
                const f4v ca = t ? c01 : c00;
                const f4v cb = t ? c11 : c10;
                const int jb = t * 16 + q4 * 4;
                float p0[4], p1[4];
#pragma unroll
                for (int rr = 0; rr < 4; rr++) {
                    int jg = J0 + jb + rr;
                    float ev = __expf(a_s[cur][jb + rr] - Mi0) * inv_sqrt_dh;
                    float ev1 = __expf(a_s[cur][jb + rr] - Mi1) * inv_sqrt_dh;
                    float pv0 = 0.f, pv1 = 0.f;
                    if (jg <= i_row0) pv0 = ca[rr] * ev;
                    if (jg <= i_row1) pv1 = cb[rr] * ev1;
                    p0[rr] = pv0; rsum0 += pv0;
                    p1[rr] = pv1; rsum1 += pv1;
                }
                int kb = t * 2 + (q4 >> 1);
                int cidx = (iq * 64 + lm * 4 + (kb ^ (lm & 3))) * 8 + (q4 & 1) * 4;
                u2v pw0, pw1;
                pw0.x = pkbf2(p0[0], p0[1]); pw0.y = pkbf2(p0[2], p0[3]);
                pw1.x = pkbf2(p1[0], p1[1]); pw1.y = pkbf2(p1[2], p1[3]);
                *(u2v*)&PF[cidx]            = pw0;
                *(u2v*)&PF[256 * 8 + cidx]  = pw1;
            }
            rsum0 += __shfl_xor(rsum0, 16);
            rsum0 += __shfl_xor(rsum0, 32);
            rs_a0 += rsum0;
            rsum1 += __shfl_xor(rsum1, 16);
            rsum1 += __shfl_xor(rsum1, 32);
            rs_a1 += rsum1;
        }
        int pidx = (iq * 64 + lm * 4 + (q4 ^ (lm & 3))) * 8;
        s8v pa0 = *(const s8v*)&PF[pidx];
        s8v pa1 = *(const s8v*)&PF[256 * 8 + pidx];

#pragma unroll
        for (int db = 0; db < 16; db++) {
            int d = db * 16 + lm;
            s8v vb = *(const s8v*)&VF[cur][(d * 4 + (q4 ^ ((d >> 1) & 3))) * 8];
            acc0[db] = __builtin_amdgcn_mfma_f32_16x16x32_bf16(pa0, vb, acc0[db], 0, 0, 0);
            acc1[db] = __builtin_amdgcn_mfma_f32_16x16x32_bf16(pa1, vb, acc1[db], 0, 0, 0);
        }
    }

    if (q4 == 0) {
        rs_s[iq * 16 + lm] = rs_a0;
        rs_s[64 + iq * 16 + lm] = rs_a1;
    }
    __syncthreads();
    if (tid < TIB)
        rsbuf[(size_t)sg * BH * Ss + (size_t)bh * Ss + I0 + tid] = rs_s[tid];

#pragma unroll
    for (int rr = 0; rr < 4; rr++) {
        float* row0 = Hdst + ((size_t)(b * Ss + I0 + iq * 16 + q4 * 4 + rr)) * Ee + hoff + lm;
        float* row1 = row0 + (size_t)64 * Ee;
#pragma unroll
        for (int db = 0; db < 16; db++) {
            row0[db * 16] = acc0[db][rr];
            row1[db * 16] = acc1[db][rr];
        }
    }
}

// ---------------------------------------------------------------------------
// Kernel 3b (fallback, inline staging, 3-barrier): kept for small workspaces.
// ---------------------------------------------------------------------------
template<int PARTS>
__global__ __launch_bounds__(256, 4) void mlstm_fallback(
    const float* __restrict__ qp, const float* __restrict__ kp, const float* __restrict__ vp,
    const float* __restrict__ a_ws, const float* __restrict__ M_ws,
    float* __restrict__ outF, float* __restrict__ Hpart, float* __restrict__ rsbuf)
{
    int bidx = blockIdx.x;
    int bh, T, sg;
    if (PARTS == 1) {
        bh = bidx & 7; T = (NT2 - 1) - (bidx >> 3); sg = 0;
    } else {
        int qd = bidx >> 8, u = bidx & 255;
        bh = u & 7;
        int r = u >> 3;
        T  = qd ? r : (31 - r);
        sg = r & 1;
    }
    int b = bh >> 2, h = bh & 3;
    int I0 = T * TI;
    int tid = threadIdx.x;

    const int tot = 2 * T + 2;
    const int jt_beg = (sg * tot) / PARTS;
    const int jt_end = ((sg + 1) * tot) / PARTS;
    const size_t hoff = (size_t)h * DHh;
    float* Hdst = (sg == 0) ? outF : (Hpart + (size_t)(sg - 1) * Bb * Ss * Ee);

    if (jt_beg >= jt_end) {
        float4 z = {0.f, 0.f, 0.f, 0.f};
        for (int t = tid; t < TI * 64; t += 256) {
            int r2 = t >> 6, c = t & 63;
            *(float4*)(Hdst + ((size_t)(b * Ss + I0 + r2)) * Ee + hoff + 4 * c) = z;
        }
        if (tid < TI) rsbuf[(size_t)sg * BH * Ss + (size_t)bh * Ss + I0 + tid] = 0.f;
        return;
    }

    __shared__ unsigned short KF[1024 * 8];
    __shared__ unsigned short VF[1024 * 8];
    __shared__ unsigned short PF[256 * 8];
    __shared__ float a_s[TJ];
    __shared__ float rs_s[TI];

    const int iq   = tid >> 6;
    const int lane = tid & 63;
    const int lm = lane & 15, q4 = lane >> 4;
    const int m5 = lane & 31, hl = lane >> 5;

    s8v qf[8];
    {
        const float* qrow = qp + ((size_t)(b * Ss + I0 + iq * 16 + lm)) * Ee + hoff;
#pragma unroll
        for (int ks = 0; ks < 8; ks++) {
            const float4* p = (const float4*)(qrow + ks * 32 + q4 * 8);
            float4 x0 = p[0], x1 = p[1];
            union { s8v v; unsigned u[4]; } rr;
            rr.u[0] = pkbf2(x0.x, x0.y);
            rr.u[1] = pkbf2(x0.z, x0.w);
            rr.u[2] = pkbf2(x1.x, x1.y);
            rr.u[3] = pkbf2(x1.z, x1.w);
            qf[ks] = rr.v;
        }
    }
    const int  i_row = I0 + iq * 16 + lm;
    const float Mi = M_ws[(size_t)bh * Ss + i_row];

    f16v acc[4];
#pragma unroll
    for (int t = 0; t < 4; t++)
#pragma unroll
        for (int i = 0; i < 16; i++) acc[t][i] = 0.f;
    float rs_acc = 0.f;

    const float inv_sqrt_dh = 0.0625f;
    const int kR  = tid >> 3, kc0 = tid & 7;
    const int vdp = tid & 127, vjb = tid >> 7;

    for (int jt = jt_beg; jt < jt_end; jt++) {
        const int J0 = jt * TJ;
        __syncthreads();
        {
            const float* src = kp + ((size_t)(b * Ss + J0 + kR)) * Ee + hoff;
#pragma unroll
            for (int p = 0; p < 4; p++) {
                int cc = kc0 + 8 * p;
                float4 x0 = ((const float4*)(src + cc * 8))[0];
                float4 x1 = ((const float4*)(src + cc * 8))[1];
                u4v wv;
                wv.x = pkbf2(x0.x, x0.y); wv.y = pkbf2(x0.z, x0.w);
                wv.z = pkbf2(x1.x, x1.y); wv.w = pkbf2(x1.z, x1.w);
                *(u4v*)&KF[(kR * 32 + (cc ^ (kR & 7))) * 8] = wv;
            }
            int d0 = vdp * 2;
#pragma unroll
            for (int p = 0; p < 2; p++) {
                int jc = vjb + 2 * p;
                const float* vbase = vp + ((size_t)(b * Ss + J0 + jc * 8)) * Ee + hoff + d0;
                float2 e0 = *(const float2*)(vbase);
                float2 e1 = *(const float2*)(vbase + Ee);
                float2 e2 = *(const float2*)(vbase + 2 * Ee);
                float2 e3 = *(const float2*)(vbase + 3 * Ee);
                float2 e4 = *(const float2*)(vbase + 4 * Ee);
                float2 e5 = *(const float2*)(vbase + 5 * Ee);
                float2 e6 = *(const float2*)(vbase + 6 * Ee);
                float2 e7 = *(const float2*)(vbase + 7 * Ee);
                int swz = jc ^ (vdp & 3);
                u4v w0, w1;
                w0.x = pkbf2(e0.x, e1.x); w0.y = pkbf2(e2.x, e3.x);
                w0.z = pkbf2(e4.x, e5.x); w0.w = pkbf2(e6.x, e7.x);
                w1.x = pkbf2(e0.y, e1.y); w1.y = pkbf2(e2.y, e3.y);
                w1.z = pkbf2(e4.y, e5.y); w1.w = pkbf2(e6.y, e7.y);
                *(u4v*)&VF[(d0 * 4 + swz) * 8] = w0;
                *(u4v*)&VF[((d0 + 1) * 4 + swz) * 8] = w1;
            }
        }
        if (tid < TJ) a_s[tid] = a_ws[(size_t)bh * Ss + J0 + tid];
        __syncthreads();

        f4v c0 = {0.f, 0.f, 0.f, 0.f}, c1 = c0;
#pragma unroll
        for (int ks = 0; ks < 8; ks++) {
            int swzk = ((ks * 4 + q4) ^ (lm & 7)) * 8;
            s8v af0 = *(const s8v*)&KF[(lm * 32) * 8 + swzk];
            s8v af1 = *(const s8v*)&KF[((16 + lm) * 32) * 8 + swzk];
            c0 = __builtin_amdgcn_mfma_f32_16x16x32_bf16(af0, qf[ks], c0, 0, 0, 0);
            c1 = __builtin_amdgcn_mfma_f32_16x16x32_bf16(af1, qf[ks], c1, 0, 0, 0);
        }
        {
            float rsum = 0.f;
#pragma unroll
            for (int t = 0; t < 2; t++) {
                const f4v cc = t ? c1 : c0;
                const int jb = t * 16 + q4 * 4;
                float p[4];
#pragma unroll
                for (int rr = 0; rr < 4; rr++) {
                    int jg = J0 + jb + rr;
                    float pv = 0.f;
                    if (jg <= i_row) pv = cc[rr] * inv_sqrt_dh * __expf(a_s[jb + rr] - Mi);
                    p[rr] = pv; rsum += pv;
                }
                u2v pwv;
                pwv.x = pkbf2(p[0], p[1]);
                pwv.y = pkbf2(p[2], p[3]);
                int i = iq * 16 + lm;
                int kb = t * 2 + (q4 >> 1);
                *(u2v*)&PF[(i * 4 + (kb ^ ((i >> 1) & 3))) * 8 + (q4 & 1) * 4] = pwv;
            }
            rsum += __shfl_xor(rsum, 16);
            rsum += __shfl_xor(rsum, 32);
            rs_acc += rsum;
        }
        __syncthreads();

#pragma unroll
        for (int ks2 = 0; ks2 < 2; ks2++) {
            int swz2 = ((ks2 * 2 + hl) ^ ((m5 >> 1) & 3)) * 8;
            s8v pa0 = *(const s8v*)&PF[(m5 * 4) * 8 + swz2];
            s8v pa1 = *(const s8v*)&PF[((32 + m5) * 4) * 8 + swz2];
            s8v vb0 = *(const s8v*)&VF[((iq * 32 + m5) * 4) * 8 + swz2];
            s8v vb1 = *(const s8v*)&VF[(((iq + 4) * 32 + m5) * 4) * 8 + swz2];
            acc[0] = __builtin_amdgcn_mfma_f32_32x32x16_bf16(pa0, vb0, acc[0], 0, 0, 0);
            acc[1] = __builtin_amdgcn_mfma_f32_32x32x16_bf16(pa0, vb1, acc[1], 0, 0, 0);
            acc[2] = __builtin_amdgcn_mfma_f32_32x32x16_bf16(pa1, vb0, acc[2], 0, 0, 0);
            acc[3] = __builtin_amdgcn_mfma_f32_32x32x16_bf16(pa1, vb1, acc[3], 0, 0, 0);
        }
    }

    if (q4 == 0) rs_s[iq * 16 + lm] = rs_acc;
    __syncthreads();
    if (tid < TI)
        rsbuf[(size_t)sg * BH * Ss + (size_t)bh * Ss + I0 + tid] = rs_s[tid];

#pragma unroll
    for (int im = 0; im < 2; im++)
#pragma unroll
        for (int ns = 0; ns < 2; ns++) {
            const f16v av = acc[im * 2 + ns];
            const int col = (iq + 4 * ns) * 32 + m5;
#pragma unroll
            for (int rr = 0; rr < 16; rr++) {
                int row = I0 + im * 32 + (rr & 3) + 8 * (rr >> 2) + 4 * hl;
                Hdst[((size_t)(b * Ss + row)) * Ee + hoff + col] = av[rr];
            }
        }
}

// ---------------------------------------------------------------------------
// Kernel 4a: combine for the chunked mapping. Per row: TI=64 tile T occupies
// global iters [T(T+1), T(T+1)+2T+2); piece count p = (chunks intersecting)
// = (tend-1)/11 - tstart/11 + 1. Same closed form as the mlstm kernel's ord.
// ---------------------------------------------------------------------------
__global__ __launch_bounds__(256) void combine_ch(
    const float* __restrict__ Hb, const float* __restrict__ rsbuf,
    const float* __restrict__ nf_ws, const float* __restrict__ out_w,
    float* __restrict__ outF)
{
    int rid = blockIdx.x * 4 + (threadIdx.x >> 6);
    int lane = threadIdx.x & 63;
    int bh = rid >> 11, s = rid & 2047;
    int b = bh >> 2, h = bh & 3;
    int T = s >> 6;                      // TI=64 tile index
    int tstart = T * (T + 1);
    int tend   = tstart + 2 * T + 2;
    int p = (tend - 1) / 11 - tstart / 11 + 1;

    size_t base = ((size_t)(b * Ss + s)) * Ee + (size_t)h * DHh + lane * 4;
    const size_t HP = (size_t)Bb * Ss * Ee;
    float4 ha = *(const float4*)(outF + base);
    float rs = rsbuf[(size_t)bh * Ss + s];
    for (int k = 1; k < p; k++) {
        float4 hb = *(const float4*)(Hb + (size_t)(k - 1) * HP + base);
        ha.x += hb.x; ha.y += hb.y; ha.z += hb.z; ha.w += hb.w;
        rs += rsbuf[(size_t)k * BH * Ss + (size_t)bh * Ss + s];
    }
    float nfv = nf_ws[(size_t)bh * Ss + s];
    float invn = 1.f / (fmaxf(fabsf(rs), nfv) + 1e-8f);
    float4 x;
    x.x = ha.x * invn; x.y = ha.y * invn; x.z = ha.z * invn; x.w = ha.w * invn;
    float sx = x.x + x.y + x.z + x.w;
    float sq = x.x*x.x + x.y*x.y + x.z*x.z + x.w*x.w;
#pragma unroll
    for (int off = 1; off < 64; off <<= 1) {
        sx += __shfl_xor(sx, off);
        sq += __shfl_xor(sq, off);
    }
    float mean = sx * (1.f / DHh);
    float var  = sq * (1.f / DHh) - mean * mean;
    float rstd = rsqrtf(var + 1e-5f);
    float4 w4 = *(const float4*)(out_w + (size_t)h * DHh + lane * 4);
    float4 o;
    o.x = (x.x - mean) * rstd * (1.f + w4.x);
    o.y = (x.y - mean) * rstd * (1.f + w4.y);
    o.z = (x.z - mean) * rstd * (1.f + w4.z);
    o.w = (x.w - mean) * rstd * (1.f + w4.w);
    *(float4*)(outF + base) = o;
}

// ---------------------------------------------------------------------------
// Kernel 4b: fixed-PARTS combine (for big2 path and fallbacks).
// ---------------------------------------------------------------------------
template<int PARTS>
__global__ __launch_bounds__(256) void combine_kernel(
    const float* __restrict__ Hb, const float* __restrict__ rsbuf,
    const float* __restrict__ nf_ws, const float* __restrict__ out_w,
    float* __restrict__ outF)
{
    int rid = blockIdx.x * 4 + (threadIdx.x >> 6);
    int lane = threadIdx.x & 63;
    int bh = rid >> 11, s = rid & 2047;
    int b = bh >> 2, h = bh & 3;
    size_t base = ((size_t)(b * Ss + s)) * Ee + (size_t)h * DHh + lane * 4;
    float4 ha = *(const float4*)(outF + base);
    float rs = rsbuf[(size_t)bh * Ss + s];
#pragma unroll
    for (int k = 1; k < PARTS; k++) {
        float4 hb = *(const float4*)(Hb + (size_t)(k - 1) * Bb * Ss * Ee + base);
        ha.x += hb.x; ha.y += hb.y; ha.z += hb.z; ha.w += hb.w;
        rs += rsbuf[(size_t)k * BH * Ss + (size_t)bh * Ss + s];
    }
    float nfv = nf_ws[(size_t)bh * Ss + s];
    float invn = 1.f / (fmaxf(fabsf(rs), nfv) + 1e-8f);
    float4 x;
    x.x = ha.x * invn; x.y = ha.y * invn; x.z = ha.z * invn; x.w = ha.w * invn;
    float sx = x.x + x.y + x.z + x.w;
    float sq = x.x*x.x + x.y*x.y + x.z*x.z + x.w*x.w;
#pragma unroll
    for (int off = 1; off < 64; off <<= 1) {
        sx += __shfl_xor(sx, off);
        sq += __shfl_xor(sq, off);
    }
    float mean = sx * (1.f / DHh);
    float var  = sq * (1.f / DHh) - mean * mean;
    float rstd = rsqrtf(var + 1e-5f);
    float4 w4 = *(const float4*)(out_w + (size_t)h * DHh + lane * 4);
    float4 o;
    o.x = (x.x - mean) * rstd * (1.f + w4.x);
    o.y = (x.y - mean) * rstd * (1.f + w4.y);
    o.z = (x.z - mean) * rstd * (1.f + w4.z);
    o.w = (x.w - mean) * rstd * (1.f + w4.w);
    *(float4*)(outF + base) = o;
}

// ---------------------------------------------------------------------------
extern "C" void kernel_launch(void* const* d_in, const int* in_sizes, int n_in,
                              void* d_out, int out_size, void* d_ws, size_t ws_size,
                              hipStream_t stream) {
    const float* q   = (const float*)d_in[0];
    const float* k   = (const float*)d_in[1];
    const float* v   = (const float*)d_in[2];
    const float* igw = (const float*)d_in[3];
    const float* igb = (const float*)d_in[4];
    const float* fgw = (const float*)d_in[5];
    const float* fgb = (const float*)d_in[6];
    const float* ow  = (const float*)d_in[7];
    float* out = (float*)d_out;

    float* ws = (float*)d_ws;
    float* ig = ws;                     // BH*S floats each
    float* fg = ws + 16384;
    float* aa = ws + 32768;
    float* MM = ws + 49152;
    float* nf = ws + 65536;
    float* rsb = ws + 81920;            // 8 slots x BH*S = 131072 floats
    const size_t base_f = 81920 + 131072;           // 212992 floats
    unsigned short* KimgP = (unsigned short*)(ws + base_f);
    const size_t img_u = (size_t)BH * NJT * 1024 * 8;        // 8.4 MB each (u16)
    unsigned short* VimgP = KimgP + img_u;
    float* HpartImg = (float*)(VimgP + img_u);
    float* HpartRaw = ws + base_f;
    const size_t HP = (size_t)Bb * Ss * Ee;                  // 16.8 MB

    const size_t need_ch = base_f * 4 + 2 * img_u * 2 + 6 * HP * 4;  // ~118 MB
    const size_t need4   = base_f * 4 + 2 * img_u * 2 + 3 * HP * 4;  // ~85 MB
    const size_t need2   = base_f * 4 + 1 * HP * 4;

    if (ws_size >= need_ch) {
        gates_prep_kernel<<<1024, 256, 0, stream>>>(q, k, v, igw, igb, fgw, fgb,
                                                    ig, fg, KimgP, VimgP);
        scan_kernel<<<BH, 256, 0, stream>>>(ig, fg, aa, MM, nf);
        mlstm_ch<<<768, 256, 0, stream>>>(q, KimgP, VimgP, aa, MM,
                                          out, HpartImg, rsb);
        combine_ch<<<BH * Ss / 4, 256, 0, stream>>>(HpartImg, rsb, nf, ow, out);
    } else if (ws_size >= need4) {
        gates_prep_kernel<<<1024, 256, 0, stream>>>(q, k, v, igw, igb, fgw, fgb,
                                                    ig, fg, KimgP, VimgP);
        scan_kernel<<<BH, 256, 0, stream>>>(ig, fg, aa, MM, nf);
        mlstm_big2<<<512, 256, 0, stream>>>(q, KimgP, VimgP, aa, MM,
                                            out, HpartImg, rsb);
        combine_kernel<4><<<BH * Ss / 4, 256, 0, stream>>>(HpartImg, rsb, nf, ow, out);
    } else if (ws_size >= need2) {
        gates_prep_kernel<<<512, 256, 0, stream>>>(q, k, v, igw, igb, fgw, fgb,
                                                   ig, fg, nullptr, nullptr);
        scan_kernel<<<BH, 256, 0, stream>>>(ig, fg, aa, MM, nf);
        mlstm_fallback<2><<<512, 256, 0, stream>>>(q, k, v, aa, MM, out, HpartRaw, rsb);
        combine_kernel<2><<<BH * Ss / 4, 256, 0, stream>>>(HpartRaw, rsb, nf, ow, out);
    } else {
        gates_prep_kernel<<<512, 256, 0, stream>>>(q, k, v, igw, igb, fgw, fgb,
                                                   ig, fg, nullptr, nullptr);
        scan_kernel<<<BH, 256, 0, stream>>>(ig, fg, aa, MM, nf);
        mlstm_fallback<1><<<256, 256, 0, stream>>>(q, k, v, aa, MM, out, HpartRaw, rsb);
        combine_kernel<1><<<BH * Ss / 4, 256, 0, stream>>>(HpartRaw, rsb, nf, ow, out);
    }
}